// Round 1
// baseline (4554.623 us; speedup 1.0000x reference)
//
#include <hip/hip_runtime.h>

#define Bb 4
#define Nn 384
#define Ee 768
#define Hh 32
#define Ff 3072
#define Ll 12
#define Ss 512
#define Dd 24
#define Mm (Nn*Bb)   // 1536 tokens

typedef __attribute__((ext_vector_type(8))) short bf16x8;
typedef __attribute__((ext_vector_type(4))) float f32x4;

__device__ __forceinline__ unsigned short f2b(float f) {
  union { float f; unsigned int i; } c; c.f = f;
  unsigned int x = c.i;
  return (unsigned short)((x + 0x7fffu + ((x >> 16) & 1u)) >> 16); // RNE
}
__device__ __forceinline__ float b2f(unsigned short u) {
  union { unsigned int i; float f; } c; c.i = ((unsigned int)u) << 16; return c.f;
}
__device__ __forceinline__ void gload_lds16(const void* g, void* l) {
  __builtin_amdgcn_global_load_lds((__attribute__((address_space(1))) void*)(g),
                                   (__attribute__((address_space(3))) void*)(l), 16, 0, 0);
}

// ---------------- embedding: x[n][b][e] = node_emb[nt] + in_deg_emb + out_deg_emb + feat
__global__ __launch_bounds__(256) void embed_kernel(
    const int* __restrict__ node_type, const float* __restrict__ nif,
    const int* __restrict__ in_deg, const int* __restrict__ out_deg,
    const float* __restrict__ node_emb, const float* __restrict__ ind_emb,
    const float* __restrict__ outd_emb,
    float* __restrict__ x, unsigned short* __restrict__ xb)
{
  const int r = blockIdx.x;           // r = n*B + b
  const int n = r / Bb, b = r % Bb;
  const int nt  = node_type[b*Nn + n];
  const int idg = in_deg[b*Nn + n];
  const int odg = out_deg[b*Nn + n];
  for (int c = threadIdx.x; c < Ee; c += 256) {
    float val = node_emb[(size_t)nt*Ee + c] + ind_emb[(size_t)idg*Ee + c]
              + outd_emb[(size_t)odg*Ee + c] + nif[((size_t)b*Nn + n)*Ee + c];
    x[(size_t)r*Ee + c] = val;
    xb[(size_t)r*Ee + c] = f2b(val);
  }
}

// ---------------- spatial_pos transpose: spT[b][n][m] = sp[b][m][n]
__global__ void spT_kernel(const int* __restrict__ sp, int* __restrict__ spT)
{
  __shared__ int tile[32][33];
  const int b = blockIdx.z;
  const int n0 = blockIdx.y * 32, m0 = blockIdx.x * 32;
  const int tx = threadIdx.x, ty = threadIdx.y;
  for (int i = ty; i < 32; i += 8)
    tile[i][tx] = sp[((size_t)b*Nn + n0 + i)*Nn + m0 + tx];
  __syncthreads();
  for (int i = ty; i < 32; i += 8)
    spT[((size_t)b*Nn + m0 + i)*Nn + n0 + tx] = tile[tx][i];
}

// ---------------- GEMM: C[M,N] = A(bf16)[M,K] @ W(f32)[K,Ncw(xseg)] + bias, epilogues
// epi 0: QKV fused (scale on seg 0 = Q), f32 out; epi 1: f32 out; epi 2: gelu -> bf16 out
__global__ __launch_bounds__(256) void gemm_kernel(
    const unsigned short* __restrict__ A,
    const float* __restrict__ W0, const float* __restrict__ W1p, const float* __restrict__ W2p,
    const float* __restrict__ bias0, const float* __restrict__ bias1, const float* __restrict__ bias2,
    int K, int Ncw, int ldOut, float scaleQ,
    float* __restrict__ outF, unsigned short* __restrict__ outB, int epi)
{
  __shared__ __align__(16) unsigned short As[2][128][32];  // [m][k]
  __shared__ __align__(16) unsigned short Ws[2][128][32];  // [n][k] (transposed during staging)
  const int t = threadIdx.x, lane = t & 63, wave = t >> 6;
  const int m0 = blockIdx.x * 128, n0 = blockIdx.y * 128;
  const int seg = n0 / Ncw;                       // which weight (qkv) — tiles never straddle
  const float* __restrict__ W    = (seg == 0) ? W0    : ((seg == 1) ? W1p   : W2p);
  const float* __restrict__ bias = (seg == 0) ? bias0 : ((seg == 1) ? bias1 : bias2);
  const int colbase = n0 - seg * Ncw;
  const float scale = (epi == 0 && seg == 0) ? scaleQ : 1.0f;
  const int nk = K >> 5;
  const int wm = wave >> 1, wn = wave & 1;
  const int sn = t & 127, sg = t >> 7;

  f32x4 acc[4][4];
  #pragma unroll
  for (int a = 0; a < 4; ++a)
    #pragma unroll
    for (int bq_ = 0; bq_ < 4; ++bq_) acc[a][bq_] = (f32x4){0.f, 0.f, 0.f, 0.f};

  // ---- prologue: stage k-tile 0
  #pragma unroll
  for (int i = 0; i < 2; ++i) {
    int byte = i*4096 + t*16;
    int row = byte >> 6, koff = (byte & 63) >> 1;
    gload_lds16(A + (size_t)(m0 + row) * K + koff,
                (char*)(&As[0][0][0]) + i*4096 + wave*1024);
  }
  #pragma unroll
  for (int i = 0; i < 4; ++i) {
    int kb = sg*4 + i*8;
    const float* wp = W + (size_t)kb * Ncw + colbase + sn;
    uint2 u;
    u.x = (unsigned)f2b(wp[0])        | ((unsigned)f2b(wp[Ncw])   << 16);
    u.y = (unsigned)f2b(wp[2*Ncw])    | ((unsigned)f2b(wp[3*Ncw]) << 16);
    *(uint2*)&Ws[0][sn][kb] = u;
  }
  __syncthreads();

  const int row16 = lane & 15, kbase = (lane >> 4) << 3;

  for (int kt = 0; kt < nk; ++kt) {
    const int cur = kt & 1, nxt = cur ^ 1;
    float wreg[16];
    const bool pre = (kt + 1 < nk);
    if (pre) {
      const int k0n = (kt + 1) << 5;
      #pragma unroll
      for (int i = 0; i < 4; ++i) {
        int kb = sg*4 + i*8;
        const float* wp = W + (size_t)(k0n + kb) * Ncw + colbase + sn;
        wreg[i*4+0] = wp[0];     wreg[i*4+1] = wp[Ncw];
        wreg[i*4+2] = wp[2*Ncw]; wreg[i*4+3] = wp[3*Ncw];
      }
      #pragma unroll
      for (int i = 0; i < 2; ++i) {
        int byte = i*4096 + t*16;
        int row = byte >> 6, koff = (byte & 63) >> 1;
        gload_lds16(A + (size_t)(m0 + row) * K + k0n + koff,
                    (char*)(&As[nxt][0][0]) + i*4096 + wave*1024);
      }
    }
    bf16x8 af[4], bfm[4];
    #pragma unroll
    for (int fm = 0; fm < 4; ++fm)
      af[fm] = *(const bf16x8*)&As[cur][wm*64 + fm*16 + row16][kbase];
    #pragma unroll
    for (int fn = 0; fn < 4; ++fn)
      bfm[fn] = *(const bf16x8*)&Ws[cur][wn*64 + fn*16 + row16][kbase];
    #pragma unroll
    for (int fm = 0; fm < 4; ++fm)
      #pragma unroll
      for (int fn = 0; fn < 4; ++fn)
        acc[fm][fn] = __builtin_amdgcn_mfma_f32_16x16x32_bf16(af[fm], bfm[fn], acc[fm][fn], 0, 0, 0);
    if (pre) {
      #pragma unroll
      for (int i = 0; i < 4; ++i) {
        int kb = sg*4 + i*8;
        uint2 u;
        u.x = (unsigned)f2b(wreg[i*4+0]) | ((unsigned)f2b(wreg[i*4+1]) << 16);
        u.y = (unsigned)f2b(wreg[i*4+2]) | ((unsigned)f2b(wreg[i*4+3]) << 16);
        *(uint2*)&Ws[nxt][sn][kb] = u;
      }
    }
    __syncthreads();
  }

  // ---- epilogue: D layout col=lane&15, row=(lane>>4)*4+j
  #pragma unroll
  for (int fm = 0; fm < 4; ++fm) {
    const int rowb = m0 + wm*64 + fm*16 + ((lane >> 4) << 2);
    #pragma unroll
    for (int fn = 0; fn < 4; ++fn) {
      const int lcol = wn*64 + fn*16 + (lane & 15);
      const int col = n0 + lcol;
      const float bv = bias[colbase + lcol];
      f32x4 v = acc[fm][fn];
      #pragma unroll
      for (int j = 0; j < 4; ++j) {
        float val = (v[j] + bv) * scale;
        if (epi == 2) {
          float x3 = val * val * val;
          float gch = 0.5f * val * (1.0f + tanhf(0.7978845608028654f * (val + 0.044715f * x3)));
          outB[(size_t)(rowb + j) * ldOut + col] = f2b(gch);
        } else {
          outF[(size_t)(rowb + j) * ldOut + col] = val;
        }
      }
    }
  }
}

// ---------------- attention: per-(b,h,64-row tile); K/V staged to LDS bf16; bias recomputed on the fly
__global__ __launch_bounds__(256) void attn_kernel(
    const float* __restrict__ qkv,       // [1536][2304] f32, q|k|v
    const float* __restrict__ atb,       // [B][N][N]
    const int* __restrict__ sp, const int* __restrict__ spT,
    const float* __restrict__ sp_emb, const float* __restrict__ sp_emb_rev, // [S][H]
    unsigned short* __restrict__ ab)     // [1536][768] bf16 out
{
  __shared__ __align__(16) unsigned short Kt[384][40]; // padded stride: conflicts + b128 alignment
  __shared__ __align__(16) unsigned short Vt[384][28];
  __shared__ float spc[512];
  __shared__ float sprc[512];
  __shared__ float probs[4][384];
  const int bid = blockIdx.x;
  const int ntile = bid % 6;
  const int h = (bid / 6) % Hh;
  const int b = bid / (6 * Hh);
  const int t = threadIdx.x, lane = t & 63, wave = t >> 6;

  for (int idx = t; idx < 384*6; idx += 256) {
    int m = idx / 6, c = idx % 6;
    size_t base = ((size_t)m * Bb + b) * 2304 + h * 24 + c * 4;
    float4 kk = *(const float4*)(qkv + base + 768);
    float4 vv = *(const float4*)(qkv + base + 1536);
    uint2 ku; ku.x = (unsigned)f2b(kk.x) | ((unsigned)f2b(kk.y) << 16);
    ku.y = (unsigned)f2b(kk.z) | ((unsigned)f2b(kk.w) << 16);
    *(uint2*)&Kt[m][c*4] = ku;
    uint2 vu; vu.x = (unsigned)f2b(vv.x) | ((unsigned)f2b(vv.y) << 16);
    vu.y = (unsigned)f2b(vv.z) | ((unsigned)f2b(vv.w) << 16);
    *(uint2*)&Vt[m][c*4] = vu;
  }
  for (int s0 = t; s0 < Ss; s0 += 256) {
    spc[s0]  = sp_emb[(size_t)s0 * Hh + h];
    sprc[s0] = sp_emb_rev[(size_t)s0 * Hh + h];
  }
  __syncthreads();

  for (int it = 0; it < 16; ++it) {
    const int n = ntile*64 + wave*16 + it;
    const size_t r = (size_t)n * Bb + b;
    float q[24];
    #pragma unroll
    for (int d = 0; d < 24; ++d) q[d] = qkv[r*2304 + h*24 + d];  // already scaled in GEMM
    const float* abrow = atb + ((size_t)b*Nn + n)*Nn;
    const int* sprow  = sp  + ((size_t)b*Nn + n)*Nn;
    const int* sptrow = spT + ((size_t)b*Nn + n)*Nn;
    float sc[6];
    #pragma unroll
    for (int c = 0; c < 6; ++c) {
      const int m = lane + (c << 6);
      float a = 0.f;
      #pragma unroll
      for (int jj = 0; jj < 3; ++jj) {
        uint4 kv = *(const uint4*)&Kt[m][jj*8];
        unsigned int uu[4] = {kv.x, kv.y, kv.z, kv.w};
        #pragma unroll
        for (int e = 0; e < 4; ++e) {
          a += q[jj*8 + e*2]     * b2f((unsigned short)(uu[e] & 0xffffu));
          a += q[jj*8 + e*2 + 1] * b2f((unsigned short)(uu[e] >> 16));
        }
      }
      // node_type >= 1 always -> padding mask provably all-false; skip it
      a += abrow[m] + spc[sprow[m]] + sprc[sptrow[m]];
      sc[c] = a;
    }
    float mx = sc[0];
    #pragma unroll
    for (int c = 1; c < 6; ++c) mx = fmaxf(mx, sc[c]);
    #pragma unroll
    for (int off = 1; off < 64; off <<= 1) mx = fmaxf(mx, __shfl_xor(mx, off, 64));
    float p[6]; float sum = 0.f;
    #pragma unroll
    for (int c = 0; c < 6; ++c) { p[c] = expf(sc[c] - mx); sum += p[c]; }
    #pragma unroll
    for (int off = 1; off < 64; off <<= 1) sum += __shfl_xor(sum, off, 64);
    const float inv = 1.0f / sum;
    #pragma unroll
    for (int c = 0; c < 6; ++c) probs[wave][lane + (c << 6)] = p[c];
    __syncthreads();   // all waves have identical trip counts
    // PV: lanes<48: g = lane&3 (m residue), pr = lane>>2 (d-pair 0..11)
    float a0 = 0.f, a1 = 0.f;
    const int g = lane & 3, pr = lane >> 2;
    if (lane < 48) {
      for (int mi = 0; mi < 96; ++mi) {
        const int m = (mi << 2) + g;
        const float pw = probs[wave][m];
        unsigned int v2 = *(const unsigned int*)&Vt[m][pr*2];
        a0 += pw * b2f((unsigned short)(v2 & 0xffffu));
        a1 += pw * b2f((unsigned short)(v2 >> 16));
      }
    }
    a0 += __shfl_xor(a0, 1, 64); a1 += __shfl_xor(a1, 1, 64);
    a0 += __shfl_xor(a0, 2, 64); a1 += __shfl_xor(a1, 2, 64);
    if (lane < 48 && g == 0) {
      unsigned int outp = (unsigned)f2b(a0 * inv) | ((unsigned)f2b(a1 * inv) << 16);
      *(unsigned int*)&ab[r*768 + h*24 + pr*2] = outp;
    }
    __syncthreads();   // probs reused next row
  }
}

// ---------------- residual + LayerNorm (two-pass, exact), writes f32 + bf16 copies
__global__ __launch_bounds__(256) void ln_kernel(
    const float* __restrict__ xin, const float* __restrict__ delta,
    const float* __restrict__ gamma, const float* __restrict__ beta,
    float* __restrict__ xout, unsigned short* __restrict__ xb)
{
  __shared__ float red[8];
  const int r = blockIdx.x, t = threadIdx.x;
  const size_t base = (size_t)r * Ee;
  float v[3];
  #pragma unroll
  for (int i = 0; i < 3; ++i) {
    int c = t + i*256;
    v[i] = xin[base + c] + delta[base + c];
  }
  float s = v[0] + v[1] + v[2];
  #pragma unroll
  for (int off = 1; off < 64; off <<= 1) s += __shfl_xor(s, off, 64);
  if ((t & 63) == 0) red[t >> 6] = s;
  __syncthreads();
  const float mean = (red[0] + red[1] + red[2] + red[3]) * (1.0f / 768.0f);
  float qs = 0.f;
  #pragma unroll
  for (int i = 0; i < 3; ++i) { float d = v[i] - mean; qs += d * d; }
  #pragma unroll
  for (int off = 1; off < 64; off <<= 1) qs += __shfl_xor(qs, off, 64);
  if ((t & 63) == 0) red[4 + (t >> 6)] = qs;
  __syncthreads();
  const float var = (red[4] + red[5] + red[6] + red[7]) * (1.0f / 768.0f);
  const float rstd = rsqrtf(var + 1e-5f);
  #pragma unroll
  for (int i = 0; i < 3; ++i) {
    int c = t + i*256;
    float o = (v[i] - mean) * rstd * gamma[c] + beta[c];
    xout[base + c] = o;
    xb[base + c] = f2b(o);
  }
}

extern "C" void kernel_launch(void* const* d_in, const int* in_sizes, int n_in,
                              void* d_out, int out_size, void* d_ws, size_t ws_size,
                              hipStream_t stream) {
  const int*   node_type  = (const int*)d_in[0];
  const float* nif        = (const float*)d_in[1];
  const int*   in_deg     = (const int*)d_in[2];
  const int*   out_deg    = (const int*)d_in[3];
  const float* atb        = (const float*)d_in[4];
  const int*   sp         = (const int*)d_in[5];
  const float* node_emb   = (const float*)d_in[6];
  const float* ind_emb    = (const float*)d_in[7];
  const float* outd_emb   = (const float*)d_in[8];
  const float* sp_emb     = (const float*)d_in[9];
  const float* sp_emb_rev = (const float*)d_in[10];
  const float* Wq = (const float*)d_in[11]; const float* bq = (const float*)d_in[12];
  const float* Wk = (const float*)d_in[13]; const float* bk = (const float*)d_in[14];
  const float* Wv = (const float*)d_in[15]; const float* bv = (const float*)d_in[16];
  const float* Wo = (const float*)d_in[17]; const float* bo = (const float*)d_in[18];
  const float* W1 = (const float*)d_in[19]; const float* b1 = (const float*)d_in[20];
  const float* W2 = (const float*)d_in[21]; const float* b2 = (const float*)d_in[22];
  const float* ln1s = (const float*)d_in[23]; const float* ln1b = (const float*)d_in[24];
  const float* ln2s = (const float*)d_in[25]; const float* ln2b = (const float*)d_in[26];

  char* ws = (char*)d_ws;
  float*          x    = (float*)(ws);                       //  4,718,592 B
  unsigned short* xb   = (unsigned short*)(ws +  4718592);   //  2,359,296
  float*          qkv  = (float*)(ws +  7077888);            // 14,155,776
  unsigned short* abuf = (unsigned short*)(ws + 21233664);   //  2,359,296
  float*          obuf = (float*)(ws + 23592960);            //  4,718,592
  unsigned short* hb   = (unsigned short*)(ws + 28311552);   //  9,437,184
  int*            spT  = (int*)(ws + 37748736);              //  2,359,296  (total ~40.1 MB)

  embed_kernel<<<Mm, 256, 0, stream>>>(node_type, nif, in_deg, out_deg,
                                       node_emb, ind_emb, outd_emb, x, xb);
  spT_kernel<<<dim3(12, 12, 4), dim3(32, 8), 0, stream>>>(sp, spT);

  const float scaleQ = 0.2041241452319315f;  // 24^-0.5

  for (int l = 0; l < Ll; ++l) {
    const float *wq = Wq + (size_t)l*Ee*Ee, *wk = Wk + (size_t)l*Ee*Ee, *wv = Wv + (size_t)l*Ee*Ee;
    const float *bql = bq + (size_t)l*Ee, *bkl = bk + (size_t)l*Ee, *bvl = bv + (size_t)l*Ee;
    const float *wo = Wo + (size_t)l*Ee*Ee, *bol = bo + (size_t)l*Ee;
    const float *w1 = W1 + (size_t)l*Ee*Ff, *b1l = b1 + (size_t)l*Ff;
    const float *w2 = W2 + (size_t)l*Ff*Ee, *b2l = b2 + (size_t)l*Ee;

    // fused QKV: [1536,768] @ [768, 3x768] -> qkv f32 (q scaled)
    gemm_kernel<<<dim3(12, 18), 256, 0, stream>>>(xb, wq, wk, wv, bql, bkl, bvl,
                                                  768, 768, 2304, scaleQ, qkv, nullptr, 0);
    attn_kernel<<<Bb*Hh*6, 256, 0, stream>>>(qkv, atb, sp, spT, sp_emb, sp_emb_rev, abuf);
    // O-proj
    gemm_kernel<<<dim3(12, 6), 256, 0, stream>>>(abuf, wo, wo, wo, bol, bol, bol,
                                                 768, 768, 768, 1.0f, obuf, nullptr, 1);
    ln_kernel<<<Mm, 256, 0, stream>>>(x, obuf, ln1s + (size_t)l*Ee, ln1b + (size_t)l*Ee, x, xb);
    // FFN1 + gelu -> bf16 hidden
    gemm_kernel<<<dim3(12, 24), 256, 0, stream>>>(xb, w1, w1, w1, b1l, b1l, b1l,
                                                  768, 3072, 3072, 1.0f, nullptr, hb, 2);
    // FFN2
    gemm_kernel<<<dim3(12, 6), 256, 0, stream>>>(hb, w2, w2, w2, b2l, b2l, b2l,
                                                 3072, 768, 768, 1.0f, obuf, nullptr, 1);
    float* xdst = (l == Ll - 1) ? (float*)d_out : x;
    ln_kernel<<<Mm, 256, 0, stream>>>(x, obuf, ln2s + (size_t)l*Ee, ln2b + (size_t)l*Ee, xdst, xb);
  }
}

// Round 2
// 1867.502 us; speedup vs baseline: 2.4389x; 2.4389x over previous
//
#include <hip/hip_runtime.h>
#include <hip/hip_bf16.h>

#define Bb 4
#define Nn 384
#define Ee 768
#define Hh 32
#define Ff 3072
#define Ll 12
#define Ss 512
#define Mm (Nn*Bb)   // 1536 tokens

typedef __attribute__((ext_vector_type(8))) short bf16x8;
typedef __attribute__((ext_vector_type(4))) float f32x4;
typedef unsigned short u16;

__device__ __forceinline__ u16 f2b(float f) {
  union { float f; unsigned int i; } c; c.f = f;
  unsigned int x = c.i;
  return (u16)((x + 0x7fffu + ((x >> 16) & 1u)) >> 16); // RNE
}
__device__ __forceinline__ float b2f(u16 u) {
  union { unsigned int i; float f; } c; c.i = ((unsigned int)u) << 16; return c.f;
}
// packed f32x2 -> bf16x2 (single HW instr, RNE)
__device__ __forceinline__ unsigned pkcvt(float lo, float hi) {
  unsigned r;
  asm("v_cvt_pk_bf16_f32 %0, %1, %2" : "=v"(r) : "v"(lo), "v"(hi));
  return r;
}
__device__ __forceinline__ void gload_lds16(const void* g, void* l) {
  __builtin_amdgcn_global_load_lds((__attribute__((address_space(1))) void*)(g),
                                   (__attribute__((address_space(3))) void*)(l), 16, 0, 0);
}

// ---------------- embedding
__global__ __launch_bounds__(256) void embed_kernel(
    const int* __restrict__ node_type, const float* __restrict__ nif,
    const int* __restrict__ in_deg, const int* __restrict__ out_deg,
    const float* __restrict__ node_emb, const float* __restrict__ ind_emb,
    const float* __restrict__ outd_emb,
    float* __restrict__ x, u16* __restrict__ xb)
{
  const int r = blockIdx.x;           // r = n*B + b
  const int n = r / Bb, b = r % Bb;
  const int nt  = node_type[b*Nn + n];
  const int idg = in_deg[b*Nn + n];
  const int odg = out_deg[b*Nn + n];
  for (int c = threadIdx.x; c < Ee; c += 256) {
    float val = node_emb[(size_t)nt*Ee + c] + ind_emb[(size_t)idg*Ee + c]
              + outd_emb[(size_t)odg*Ee + c] + nif[((size_t)b*Nn + n)*Ee + c];
    x[(size_t)r*Ee + c] = val;
    xb[(size_t)r*Ee + c] = f2b(val);
  }
}

// ---------------- spatial_pos transpose
__global__ void spT_kernel(const int* __restrict__ sp, int* __restrict__ spT)
{
  __shared__ int tile[32][33];
  const int b = blockIdx.z;
  const int n0 = blockIdx.y * 32, m0 = blockIdx.x * 32;
  const int tx = threadIdx.x, ty = threadIdx.y;
  for (int i = ty; i < 32; i += 8)
    tile[i][tx] = sp[((size_t)b*Nn + n0 + i)*Nn + m0 + tx];
  __syncthreads();
  for (int i = ty; i < 32; i += 8)
    spT[((size_t)b*Nn + m0 + i)*Nn + n0 + tx] = tile[tx][i];
}

// ---------------- bias precompute: biasb[b][h][n][m] bf16 = atb + sp_emb[sp] + sp_emb_rev[spT]
__global__ __launch_bounds__(256) void bias_pre_kernel(
    const float* __restrict__ atb, const int* __restrict__ sp, const int* __restrict__ spT,
    const float* __restrict__ sp_emb, const float* __restrict__ sp_emb_rev,
    u16* __restrict__ biasb)
{
  __shared__ float spcl[512][8];
  __shared__ float sprcl[512][8];
  const int nt16 = blockIdx.x, hg = blockIdx.y, b = blockIdx.z;
  const int t = threadIdx.x;
  for (int idx = t; idx < 4096; idx += 256) {
    int s = idx >> 3, hh = idx & 7;
    spcl[s][hh]  = sp_emb[(size_t)s*Hh + hg*8 + hh];
    sprcl[s][hh] = sp_emb_rev[(size_t)s*Hh + hg*8 + hh];
  }
  __syncthreads();
  const int hh = t >> 5, ml = t & 31;
  const int h = hg*8 + hh;
  for (int nn = 0; nn < 16; ++nn) {
    const int n = nt16*16 + nn;
    const size_t rowb = ((size_t)b*Nn + n)*Nn;
    for (int mc = 0; mc < 12; ++mc) {
      const int m = mc*32 + ml;
      int s_  = sp[rowb + m];
      int sT_ = spT[rowb + m];
      float v = atb[rowb + m] + spcl[s_][hh] + sprcl[sT_][hh];
      biasb[(((size_t)b*Hh + h)*Nn + n)*Nn + m] = f2b(v);
    }
  }
}

// ---------------- weight transpose+convert: src f32 [Ks][Ns] -> dst bf16 [Ns][Ks]
__global__ __launch_bounds__(256) void wconv_kernel(
    const float* __restrict__ Wq, const float* __restrict__ Wk, const float* __restrict__ Wv,
    const float* __restrict__ Wo, const float* __restrict__ W1, const float* __restrict__ W2,
    int layer,
    u16* __restrict__ qkvT, u16* __restrict__ woT, u16* __restrict__ w1T, u16* __restrict__ w2T)
{
  __shared__ float tile[32][33];
  int tid = blockIdx.x;
  const float* src; u16* dst; int Ns, Ks;
  if (tid < 1728)      { int seg = tid / 576; tid -= seg*576;
                         src = (seg==0?Wq:(seg==1?Wk:Wv)) + (size_t)layer*Ee*Ee;
                         dst = qkvT + (size_t)seg*Ee*Ee; Ns = 768; Ks = 768; }
  else if (tid < 2304) { tid -= 1728; src = Wo + (size_t)layer*Ee*Ee; dst = woT; Ns = 768; Ks = 768; }
  else if (tid < 4608) { tid -= 2304; src = W1 + (size_t)layer*Ee*Ff; dst = w1T; Ns = 3072; Ks = 768; }
  else                 { tid -= 4608; src = W2 + (size_t)layer*Ff*Ee; dst = w2T; Ns = 768; Ks = 3072; }
  const int tcols = Ns >> 5;
  const int tk = tid / tcols, tn = tid % tcols;
  const int tx = threadIdx.x, ty = threadIdx.y;
  for (int i = ty; i < 32; i += 8)
    tile[i][tx] = src[(size_t)(tk*32 + i)*Ns + tn*32 + tx];
  __syncthreads();
  const int lin = ty*32 + tx;
  #pragma unroll
  for (int ii = 0; ii < 2; ++ii) {
    int o = lin + ii*256;
    int nn = o >> 4, kx = o & 15;
    unsigned u = pkcvt(tile[2*kx][nn], tile[2*kx+1][nn]);
    *(unsigned*)(dst + (size_t)(tn*32 + nn)*Ks + tk*32 + 2*kx) = u;
  }
}

// ---------------- GEMM: C[M,N] = A(bf16 [M][K]) @ B(bf16 [N][K], pre-transposed) + bias
// EPI 0: qkv fused (3 bias segs, Q scaled), f32 out ld=2304
// EPI 1: f32 out + bias, ld=768
// EPI 2: gelu -> bf16 out, ld=3072
template<int TILE, int EPI>
__global__ __launch_bounds__(256) void gemm2_kernel(
    const u16* __restrict__ A, const u16* __restrict__ B,
    const float* __restrict__ b0, const float* __restrict__ b1, const float* __restrict__ b2,
    int K, float scaleQ, float* __restrict__ outF, u16* __restrict__ outB)
{
  constexpr int FR = TILE / 32;
  constexpr int HALF = TILE / 2;
  constexpr int NLD = TILE / 64;     // gload insts per operand per ktile
  __shared__ __align__(16) u16 As[2][TILE][32];
  __shared__ __align__(16) u16 Bs[2][TILE][32];
  const int t = threadIdx.x, lane = t & 63, wave = t >> 6;
  const int m0 = blockIdx.x * TILE, n0 = blockIdx.y * TILE;
  const int wm = wave >> 1, wn = wave & 1;
  const int ql = lane & 15, hi = lane >> 4;
  const int kbase = hi * 8;
  const int nk = K >> 5;
  const int srow = (t * 16) >> 6;       // row covered by this thread within a 4KB chunk
  const int skoff = (t & 3) * 8;

  f32x4 acc[FR][FR];
  #pragma unroll
  for (int a = 0; a < FR; ++a)
    #pragma unroll
    for (int c = 0; c < FR; ++c) acc[a][c] = (f32x4){0.f,0.f,0.f,0.f};

  // prologue
  #pragma unroll
  for (int i = 0; i < NLD; ++i) {
    gload_lds16(A + (size_t)(m0 + i*64 + srow)*K + skoff,
                (char*)&As[0][0][0] + i*4096 + wave*1024);
    gload_lds16(B + (size_t)(n0 + i*64 + srow)*K + skoff,
                (char*)&Bs[0][0][0] + i*4096 + wave*1024);
  }
  __syncthreads();

  for (int kt = 0; kt < nk; ++kt) {
    const int cur = kt & 1, nxt = cur ^ 1;
    if (kt + 1 < nk) {
      const int k0n = (kt + 1) << 5;
      #pragma unroll
      for (int i = 0; i < NLD; ++i) {
        gload_lds16(A + (size_t)(m0 + i*64 + srow)*K + k0n + skoff,
                    (char*)&As[nxt][0][0] + i*4096 + wave*1024);
        gload_lds16(B + (size_t)(n0 + i*64 + srow)*K + k0n + skoff,
                    (char*)&Bs[nxt][0][0] + i*4096 + wave*1024);
      }
    }
    bf16x8 af[FR], bfm[FR];
    #pragma unroll
    for (int f = 0; f < FR; ++f)
      af[f] = *(const bf16x8*)&As[cur][wm*HALF + f*16 + ql][kbase];
    #pragma unroll
    for (int f = 0; f < FR; ++f)
      bfm[f] = *(const bf16x8*)&Bs[cur][wn*HALF + f*16 + ql][kbase];
    #pragma unroll
    for (int fm = 0; fm < FR; ++fm)
      #pragma unroll
      for (int fn = 0; fn < FR; ++fn)
        acc[fm][fn] = __builtin_amdgcn_mfma_f32_16x16x32_bf16(af[fm], bfm[fn], acc[fm][fn], 0, 0, 0);
    __syncthreads();
  }

  const int ldOut = (EPI == 0) ? 2304 : ((EPI == 2) ? 3072 : 768);
  #pragma unroll
  for (int fm = 0; fm < FR; ++fm) {
    const int rowb = m0 + wm*HALF + fm*16 + hi*4;
    #pragma unroll
    for (int fn = 0; fn < FR; ++fn) {
      const int gcol = n0 + wn*HALF + fn*16 + ql;
      float bv, scale = 1.0f;
      if (EPI == 0) {
        const int seg = gcol / 768;
        const int cw = gcol - seg*768;
        bv = (seg == 0) ? b0[cw] : ((seg == 1) ? b1[cw] : b2[cw]);
        if (seg == 0) scale = scaleQ;
      } else {
        bv = b0[gcol];
      }
      f32x4 v = acc[fm][fn];
      #pragma unroll
      for (int j = 0; j < 4; ++j) {
        float val = (v[j] + bv) * scale;
        if (EPI == 2) {
          float arg = 0.7978845608028654f * (val + 0.044715f * val * val * val);
          float e = __expf(2.0f * arg);
          float g = 0.5f * val * (2.0f - 2.0f / (e + 1.0f));
          outB[(size_t)(rowb + j) * ldOut + gcol] = f2b(g);
        } else {
          outF[(size_t)(rowb + j) * ldOut + gcol] = val;
        }
      }
    }
  }
}

// ---------------- MFMA attention: block = (b, h, 64-q-row tile); full-row softmax
// S^T = mfma(K, Q)  -> lane holds S^T[m = t*16+hi*4+j][q = q0+ql]
// PV: P routed via wave-private LDS chunk -> O = mfma(P, V^T)
template<int PREBIAS>
__global__ __launch_bounds__(256) void attn2_kernel(
    const float* __restrict__ qkv,       // [1536][2304] f32 q|k|v (q pre-scaled)
    const u16* __restrict__ biasb,       // [B][H][N][N] bf16 (PREBIAS=1)
    const float* __restrict__ atb, const int* __restrict__ sp, const int* __restrict__ spT,
    const float* __restrict__ sp_emb, const float* __restrict__ sp_emb_rev,
    u16* __restrict__ ab)                // [1536][768] bf16
{
  __shared__ __align__(16) u16 Kt[384][32];   // [m][d(24)+pad]
  __shared__ __align__(16) u16 Vt[32][392];   // [d(24)+pad][m] transposed
  __shared__ __align__(16) u16 Qt[64][32];
  __shared__ __align__(16) u16 Pw[4][16][32]; // per-wave P chunk [q][m']
  __shared__ float spc[512], sprc[512];
  const int bid = blockIdx.x;
  const int ntile = bid % 6;
  const int h = (bid / 6) % Hh;
  const int b = bid / (6 * Hh);
  const int t = threadIdx.x, lane = t & 63, wave = t >> 6;
  const int ql = lane & 15, hi = lane >> 4;

  // ---- stage K (bf16 [m][d]) and V^T (bf16 [d][m])
  for (int idx = t; idx < 384*6; idx += 256) {
    const int m = idx / 6, c = idx - m*6;
    const float* base = qkv + ((size_t)m*Bb + b)*2304 + h*24 + c*4;
    float4 kk = *(const float4*)(base + 768);
    float4 vv = *(const float4*)(base + 1536);
    *(uint2*)&Kt[m][c*4] = make_uint2(pkcvt(kk.x, kk.y), pkcvt(kk.z, kk.w));
    Vt[c*4+0][m] = f2b(vv.x); Vt[c*4+1][m] = f2b(vv.y);
    Vt[c*4+2][m] = f2b(vv.z); Vt[c*4+3][m] = f2b(vv.w);
  }
  for (int idx = t; idx < 384*2; idx += 256)           // K d-pad
    *(uint2*)&Kt[idx>>1][24 + (idx&1)*4] = make_uint2(0u, 0u);
  for (int idx = t; idx < 8*196; idx += 256)           // V^T d-pad rows
    *(unsigned*)((char*)&Vt[24][0] + idx*4) = 0u;
  // ---- stage Q rows of this tile
  for (int idx = t; idx < 64*6; idx += 256) {
    const int qr = idx / 6, c = idx - qr*6;
    const float* base = qkv + ((size_t)(ntile*64 + qr)*Bb + b)*2304 + h*24 + c*4;
    float4 qq = *(const float4*)base;
    *(uint2*)&Qt[qr][c*4] = make_uint2(pkcvt(qq.x, qq.y), pkcvt(qq.z, qq.w));
  }
  for (int idx = t; idx < 64*2; idx += 256)
    *(uint2*)&Qt[idx>>1][24 + (idx&1)*4] = make_uint2(0u, 0u);
  if (!PREBIAS) {
    for (int i = t; i < 512; i += 256) {
      spc[i]  = sp_emb[(size_t)i*Hh + h];
      sprc[i] = sp_emb_rev[(size_t)i*Hh + h];
    }
  }
  __syncthreads();

  const int q0 = ntile*64 + wave*16;
  const int q = q0 + ql;                                // this lane's score column
  const bf16x8 qf = *(const bf16x8*)&Qt[wave*16 + ql][hi*8];

  // ---- S^T = K @ Q^T + bias
  f32x4 f[24];
  const u16* bp = biasb + (((size_t)b*Hh + h)*Nn + q)*Nn;
  const size_t crow = ((size_t)b*Nn + q)*Nn;
  #pragma unroll
  for (int tt = 0; tt < 24; ++tt) {
    bf16x8 kf = *(const bf16x8*)&Kt[tt*16 + ql][hi*8];
    f32x4 z = (f32x4){0.f,0.f,0.f,0.f};
    f32x4 s = __builtin_amdgcn_mfma_f32_16x16x32_bf16(kf, qf, z, 0, 0, 0);
    if (PREBIAS) {
      uint2 bb = *(const uint2*)(bp + tt*16 + hi*4);
      s[0] += b2f((u16)(bb.x & 0xffffu)); s[1] += b2f((u16)(bb.x >> 16));
      s[2] += b2f((u16)(bb.y & 0xffffu)); s[3] += b2f((u16)(bb.y >> 16));
    } else {
      const int off = tt*16 + hi*4;
      int4 s4 = *(const int4*)(sp + crow + off);
      int4 t4 = *(const int4*)(spT + crow + off);
      float4 a4 = *(const float4*)(atb + crow + off);
      s[0] += a4.x + spc[s4.x] + sprc[t4.x];
      s[1] += a4.y + spc[s4.y] + sprc[t4.y];
      s[2] += a4.z + spc[s4.z] + sprc[t4.z];
      s[3] += a4.w + spc[s4.w] + sprc[t4.w];
    }
    f[tt] = s;
  }

  // ---- softmax over m (column q): lane-local 96 + cross-hi reduce
  float mx = -3.0e38f;
  #pragma unroll
  for (int tt = 0; tt < 24; ++tt)
    mx = fmaxf(mx, fmaxf(fmaxf(f[tt][0], f[tt][1]), fmaxf(f[tt][2], f[tt][3])));
  mx = fmaxf(mx, __shfl_xor(mx, 16, 64));
  mx = fmaxf(mx, __shfl_xor(mx, 32, 64));
  float sum = 0.f;
  #pragma unroll
  for (int tt = 0; tt < 24; ++tt) {
    #pragma unroll
    for (int j = 0; j < 4; ++j) { f[tt][j] = __expf(f[tt][j] - mx); sum += f[tt][j]; }
  }
  sum += __shfl_xor(sum, 16, 64);
  sum += __shfl_xor(sum, 32, 64);
  const float inv = 1.0f / sum;

  // ---- PV: per 32-m chunk, pack P to wave-private LDS, read A-frag, 2 MFMA
  f32x4 o0 = (f32x4){0.f,0.f,0.f,0.f}, o1 = (f32x4){0.f,0.f,0.f,0.f};
  char* prow = (char*)&Pw[wave][ql][0];
  const int swz = (ql & 3) << 4;
  #pragma unroll
  for (int c = 0; c < 12; ++c) {
    unsigned w0 = pkcvt(f[2*c][0],   f[2*c][1]);
    unsigned w1 = pkcvt(f[2*c][2],   f[2*c][3]);
    unsigned w2 = pkcvt(f[2*c+1][0], f[2*c+1][1]);
    unsigned w3 = pkcvt(f[2*c+1][2], f[2*c+1][3]);
    *(unsigned*)(prow + (((hi*8)      ) ^ swz)) = w0;
    *(unsigned*)(prow + (((hi*8) +  4) ^ swz)) = w1;
    *(unsigned*)(prow + (((hi*8) + 32) ^ swz)) = w2;
    *(unsigned*)(prow + (((hi*8) + 36) ^ swz)) = w3;
    bf16x8 a = *(const bf16x8*)(prow + ((hi*16) ^ swz));
    bf16x8 v0 = *(const bf16x8*)&Vt[ql][c*32 + hi*8];
    bf16x8 v1 = *(const bf16x8*)&Vt[16 + ql][c*32 + hi*8];
    o0 = __builtin_amdgcn_mfma_f32_16x16x32_bf16(a, v0, o0, 0, 0, 0);
    o1 = __builtin_amdgcn_mfma_f32_16x16x32_bf16(a, v1, o1, 0, 0, 0);
  }

  // ---- scale by 1/sum (per OUTPUT row q' = q0+hi*4+j) and store
  #pragma unroll
  for (int j = 0; j < 4; ++j) {
    float invj = __shfl(inv, hi*4 + j, 64);
    const int qg = q0 + hi*4 + j;
    u16* orow = ab + ((size_t)qg*Bb + b)*Ee + h*24;
    orow[ql] = f2b(o0[j] * invj);
    if (ql < 8) orow[16 + ql] = f2b(o1[j] * invj);
  }
}

// ---------------- residual + LayerNorm
__global__ __launch_bounds__(256) void ln_kernel(
    const float* __restrict__ xin, const float* __restrict__ delta,
    const float* __restrict__ gamma, const float* __restrict__ beta,
    float* __restrict__ xout, u16* __restrict__ xb)
{
  __shared__ float red[8];
  const int r = blockIdx.x, t = threadIdx.x;
  const size_t base = (size_t)r * Ee;
  float v[3];
  #pragma unroll
  for (int i = 0; i < 3; ++i) {
    int c = t + i*256;
    v[i] = xin[base + c] + delta[base + c];
  }
  float s = v[0] + v[1] + v[2];
  #pragma unroll
  for (int off = 1; off < 64; off <<= 1) s += __shfl_xor(s, off, 64);
  if ((t & 63) == 0) red[t >> 6] = s;
  __syncthreads();
  const float mean = (red[0] + red[1] + red[2] + red[3]) * (1.0f / 768.0f);
  float qs = 0.f;
  #pragma unroll
  for (int i = 0; i < 3; ++i) { float d = v[i] - mean; qs += d * d; }
  #pragma unroll
  for (int off = 1; off < 64; off <<= 1) qs += __shfl_xor(qs, off, 64);
  if ((t & 63) == 0) red[4 + (t >> 6)] = qs;
  __syncthreads();
  const float var = (red[4] + red[5] + red[6] + red[7]) * (1.0f / 768.0f);
  const float rstd = rsqrtf(var + 1e-5f);
  #pragma unroll
  for (int i = 0; i < 3; ++i) {
    int c = t + i*256;
    float o = (v[i] - mean) * rstd * gamma[c] + beta[c];
    xout[base + c] = o;
    xb[base + c] = f2b(o);
  }
}

extern "C" void kernel_launch(void* const* d_in, const int* in_sizes, int n_in,
                              void* d_out, int out_size, void* d_ws, size_t ws_size,
                              hipStream_t stream) {
  const int*   node_type  = (const int*)d_in[0];
  const float* nif        = (const float*)d_in[1];
  const int*   in_deg     = (const int*)d_in[2];
  const int*   out_deg    = (const int*)d_in[3];
  const float* atb        = (const float*)d_in[4];
  const int*   sp         = (const int*)d_in[5];
  const float* node_emb   = (const float*)d_in[6];
  const float* ind_emb    = (const float*)d_in[7];
  const float* outd_emb   = (const float*)d_in[8];
  const float* sp_emb     = (const float*)d_in[9];
  const float* sp_emb_rev = (const float*)d_in[10];
  const float* Wq = (const float*)d_in[11]; const float* bq = (const float*)d_in[12];
  const float* Wk = (const float*)d_in[13]; const float* bk = (const float*)d_in[14];
  const float* Wv = (const float*)d_in[15]; const float* bv = (const float*)d_in[16];
  const float* Wo = (const float*)d_in[17]; const float* bo = (const float*)d_in[18];
  const float* W1 = (const float*)d_in[19]; const float* b1 = (const float*)d_in[20];
  const float* W2 = (const float*)d_in[21]; const float* b2 = (const float*)d_in[22];
  const float* ln1s = (const float*)d_in[23]; const float* ln1b = (const float*)d_in[24];
  const float* ln2s = (const float*)d_in[25]; const float* ln2b = (const float*)d_in[26];

  char* ws = (char*)d_ws;
  float* x    = (float*)(ws);                         //  4,718,592
  u16*   xb   = (u16*)(ws + 4718592);                 //  2,359,296
  float* qkvb = (float*)(ws + 7077888);               // 14,155,776 (R)
  float* obuf = (float*)(ws + 7077888);               //   alias R+0 (post-attn)
  u16*   hb   = (u16*)(ws + 7077888 + 4718592);       //   alias R+4.7MB
  u16*   abuf = (u16*)(ws + 21233664);                //  2,359,296
  int*   spTb = (int*)(ws + 23592960);                //  2,359,296
  u16*   qkvT = (u16*)(ws + 25952256);                //  3,538,944
  u16*   woT  = (u16*)(ws + 25952256 + 3538944);      //  1,179,648
  u16*   w1T  = (u16*)(ws + 25952256 + 4718592);      //  4,718,592
  u16*   w2T  = (u16*)(ws + 25952256 + 9437184);      //  4,718,592   (-> 40,108,032)
  u16*   biasb= (u16*)(ws + 40108032);                // 37,748,736   (-> 77,856,768)

  const bool tierB = (ws_size >= 77856768);

  embed_kernel<<<Mm, 256, 0, stream>>>(node_type, nif, in_deg, out_deg,
                                       node_emb, ind_emb, outd_emb, x, xb);
  spT_kernel<<<dim3(12, 12, 4), dim3(32, 8), 0, stream>>>(sp, spTb);
  if (tierB)
    bias_pre_kernel<<<dim3(24, 4, 4), 256, 0, stream>>>(atb, sp, spTb, sp_emb, sp_emb_rev, biasb);

  const float scaleQ = 0.2041241452319315f;  // 24^-0.5

  for (int l = 0; l < Ll; ++l) {
    const float *bql = bq + (size_t)l*Ee, *bkl = bk + (size_t)l*Ee, *bvl = bv + (size_t)l*Ee;
    const float *bol = bo + (size_t)l*Ee;
    const float *b1l = b1 + (size_t)l*Ff, *b2l = b2 + (size_t)l*Ee;

    wconv_kernel<<<6912, dim3(32, 8), 0, stream>>>(Wq, Wk, Wv, Wo, W1, W2, l,
                                                   qkvT, woT, w1T, w2T);
    gemm2_kernel<128,0><<<dim3(12, 18), 256, 0, stream>>>(xb, qkvT, bql, bkl, bvl,
                                                          768, scaleQ, qkvb, nullptr);
    if (tierB)
      attn2_kernel<1><<<768, 256, 0, stream>>>(qkvb, biasb, atb, sp, spTb,
                                               sp_emb, sp_emb_rev, abuf);
    else
      attn2_kernel<0><<<768, 256, 0, stream>>>(qkvb, nullptr, atb, sp, spTb,
                                               sp_emb, sp_emb_rev, abuf);
    gemm2_kernel<64,1><<<dim3(24, 12), 256, 0, stream>>>(abuf, woT, bol, bol, bol,
                                                         768, 1.0f, obuf, nullptr);
    ln_kernel<<<Mm, 256, 0, stream>>>(x, obuf, ln1s + (size_t)l*Ee, ln1b + (size_t)l*Ee, x, xb);
    gemm2_kernel<128,2><<<dim3(12, 24), 256, 0, stream>>>(xb, w1T, b1l, b1l, b1l,
                                                          768, 1.0f, nullptr, hb);
    gemm2_kernel<64,1><<<dim3(24, 12), 256, 0, stream>>>(hb, w2T, b2l, b2l, b2l,
                                                         3072, 1.0f, obuf, nullptr);
    float* xdst = (l == Ll - 1) ? (float*)d_out : x;
    ln_kernel<<<Mm, 256, 0, stream>>>(x, obuf, ln2s + (size_t)l*Ee, ln2b + (size_t)l*Ee, xdst, xb);
  }
}

// Round 3
// 1594.145 us; speedup vs baseline: 2.8571x; 1.1715x over previous
//
#include <hip/hip_runtime.h>
#include <hip/hip_bf16.h>

#define Bb 4
#define Nn 384
#define Ee 768
#define Hh 32
#define Ff 3072
#define Ll 12
#define Ss 512
#define Mm (Nn*Bb)   // 1536 tokens

typedef __attribute__((ext_vector_type(8))) short bf16x8;
typedef __attribute__((ext_vector_type(4))) float f32x4;
typedef unsigned short u16;

__device__ __forceinline__ u16 f2b(float f) {
  union { float f; unsigned int i; } c; c.f = f;
  unsigned int x = c.i;
  return (u16)((x + 0x7fffu + ((x >> 16) & 1u)) >> 16); // RNE
}
__device__ __forceinline__ float b2f(u16 u) {
  union { unsigned int i; float f; } c; c.i = ((unsigned int)u) << 16; return c.f;
}
__device__ __forceinline__ unsigned pkcvt(float lo, float hi) {
  unsigned r;
  asm("v_cvt_pk_bf16_f32 %0, %1, %2" : "=v"(r) : "v"(lo), "v"(hi));
  return r;
}
__device__ __forceinline__ void gload_lds16(const void* g, void* l) {
  __builtin_amdgcn_global_load_lds((__attribute__((address_space(1))) void*)(g),
                                   (__attribute__((address_space(3))) void*)(l), 16, 0, 0);
}

// ---------------- embedding
__global__ __launch_bounds__(256) void embed_kernel(
    const int* __restrict__ node_type, const float* __restrict__ nif,
    const int* __restrict__ in_deg, const int* __restrict__ out_deg,
    const float* __restrict__ node_emb, const float* __restrict__ ind_emb,
    const float* __restrict__ outd_emb,
    float* __restrict__ x, u16* __restrict__ xb)
{
  const int r = blockIdx.x;           // r = n*B + b
  const int n = r / Bb, b = r % Bb;
  const int nt  = node_type[b*Nn + n];
  const int idg = in_deg[b*Nn + n];
  const int odg = out_deg[b*Nn + n];
  for (int c = threadIdx.x; c < Ee; c += 256) {
    float val = node_emb[(size_t)nt*Ee + c] + ind_emb[(size_t)idg*Ee + c]
              + outd_emb[(size_t)odg*Ee + c] + nif[((size_t)b*Nn + n)*Ee + c];
    x[(size_t)r*Ee + c] = val;
    xb[(size_t)r*Ee + c] = f2b(val);
  }
}

// ---------------- spatial_pos transpose
__global__ void spT_kernel(const int* __restrict__ sp, int* __restrict__ spT)
{
  __shared__ int tile[32][33];
  const int b = blockIdx.z;
  const int n0 = blockIdx.y * 32, m0 = blockIdx.x * 32;
  const int tx = threadIdx.x, ty = threadIdx.y;
  for (int i = ty; i < 32; i += 8)
    tile[i][tx] = sp[((size_t)b*Nn + n0 + i)*Nn + m0 + tx];
  __syncthreads();
  for (int i = ty; i < 32; i += 8)
    spT[((size_t)b*Nn + m0 + i)*Nn + n0 + tx] = tile[tx][i];
}

// ---------------- bias precompute: biasb[b][h][n][m] bf16
__global__ __launch_bounds__(256) void bias_pre_kernel(
    const float* __restrict__ atb, const int* __restrict__ sp, const int* __restrict__ spT,
    const float* __restrict__ sp_emb, const float* __restrict__ sp_emb_rev,
    u16* __restrict__ biasb)
{
  __shared__ float spcl[512][8];
  __shared__ float sprcl[512][8];
  const int nt16 = blockIdx.x, hg = blockIdx.y, b = blockIdx.z;
  const int t = threadIdx.x;
  for (int idx = t; idx < 4096; idx += 256) {
    int s = idx >> 3, hh = idx & 7;
    spcl[s][hh]  = sp_emb[(size_t)s*Hh + hg*8 + hh];
    sprcl[s][hh] = sp_emb_rev[(size_t)s*Hh + hg*8 + hh];
  }
  __syncthreads();
  const int hh = t >> 5, ml = t & 31;
  const int h = hg*8 + hh;
  for (int nn = 0; nn < 16; ++nn) {
    const int n = nt16*16 + nn;
    const size_t rowb = ((size_t)b*Nn + n)*Nn;
    for (int mc = 0; mc < 12; ++mc) {
      const int m = mc*32 + ml;
      int s_  = sp[rowb + m];
      int sT_ = spT[rowb + m];
      float v = atb[rowb + m] + spcl[s_][hh] + sprcl[sT_][hh];
      biasb[(((size_t)b*Hh + h)*Nn + n)*Nn + m] = f2b(v);
    }
  }
}

// ---------------- weight transpose+convert: per layer slot [qkv|wo|w1|w2] bf16 [Ns][Ks]
__global__ __launch_bounds__(256) void wconv_kernel(
    const float* __restrict__ Wq, const float* __restrict__ Wk, const float* __restrict__ Wv,
    const float* __restrict__ Wo, const float* __restrict__ W1, const float* __restrict__ W2,
    int layer0, u16* __restrict__ wTall, unsigned slotStride)
{
  __shared__ float tile[32][33];
  const int layer = layer0 + blockIdx.y;
  u16* slot = wTall + (size_t)blockIdx.y * slotStride;
  int tid = blockIdx.x;
  const float* src; u16* dst; int Ns, Ks;
  if (tid < 1728)      { int seg = tid / 576; tid -= seg*576;
                         src = (seg==0?Wq:(seg==1?Wk:Wv)) + (size_t)layer*Ee*Ee;
                         dst = slot + (size_t)seg*Ee*Ee; Ns = 768; Ks = 768; }
  else if (tid < 2304) { tid -= 1728; src = Wo + (size_t)layer*Ee*Ee; dst = slot + 1769472; Ns = 768; Ks = 768; }
  else if (tid < 4608) { tid -= 2304; src = W1 + (size_t)layer*Ee*Ff; dst = slot + 2359296; Ns = 3072; Ks = 768; }
  else                 { tid -= 4608; src = W2 + (size_t)layer*Ff*Ee; dst = slot + 4718592; Ns = 768; Ks = 3072; }
  const int tcols = Ns >> 5;
  const int tk = tid / tcols, tn = tid % tcols;
  const int tx = threadIdx.x, ty = threadIdx.y;
  for (int i = ty; i < 32; i += 8)
    tile[i][tx] = src[(size_t)(tk*32 + i)*Ns + tn*32 + tx];
  __syncthreads();
  const int lin = ty*32 + tx;
  #pragma unroll
  for (int ii = 0; ii < 2; ++ii) {
    int o = lin + ii*256;
    int nn = o >> 4, kx = o & 15;
    unsigned u = pkcvt(tile[2*kx][nn], tile[2*kx+1][nn]);
    *(unsigned*)(dst + (size_t)(tn*32 + nn)*Ks + tk*32 + 2*kx) = u;
  }
}

// ---------------- 64x64-tile GEMM, split-K capable, XCD-swizzled
// EPI 0: qkv fused bias (Q scaled) -> bf16 out ld 2304
// EPI 1: f32 partial out ld 768 (bias only on z==0)
// EPI 2: gelu -> bf16 out ld 3072
template<int EPI>
__global__ __launch_bounds__(256) void gemm3_kernel(
    const u16* __restrict__ A, const u16* __restrict__ Bw,
    const float* __restrict__ b0, const float* __restrict__ b1, const float* __restrict__ b2,
    int Kfull, int Kc, float scaleQ,
    float* __restrict__ outF, u16* __restrict__ outB)
{
  __shared__ __align__(16) u16 As[2][64][32];
  __shared__ __align__(16) u16 Bs[2][64][32];
  const int t = threadIdx.x, lane = t & 63, wave = t >> 6;
  int bx = blockIdx.x, by = blockIdx.y;
  { // XCD swizzle (xy grid always divisible by 8)
    const int gx = gridDim.x;
    const int nwg = gx * gridDim.y;
    const int bid = bx + gx * by;
    const int cpx = nwg >> 3;
    const int s = (bid & 7) * cpx + (bid >> 3);
    bx = s % gx; by = s / gx;
  }
  const int m0 = bx * 64, n0 = by * 64;
  const int k0 = blockIdx.z * Kc;
  const int wm = wave >> 1, wn = wave & 1;
  const int ql = lane & 15, hi = lane >> 4;
  const int kbase = hi * 8;
  const int nk = Kc >> 5;
  const int srow = t >> 2;
  const int skoff = (t & 3) * 8;

  f32x4 acc[2][2];
  #pragma unroll
  for (int a = 0; a < 2; ++a)
    #pragma unroll
    for (int c = 0; c < 2; ++c) acc[a][c] = (f32x4){0.f,0.f,0.f,0.f};

  gload_lds16(A  + (size_t)(m0 + srow)*Kfull + k0 + skoff, (char*)&As[0][0][0] + wave*1024);
  gload_lds16(Bw + (size_t)(n0 + srow)*Kfull + k0 + skoff, (char*)&Bs[0][0][0] + wave*1024);
  __syncthreads();

  for (int kt = 0; kt < nk; ++kt) {
    const int cur = kt & 1, nxt = cur ^ 1;
    if (kt + 1 < nk) {
      const int kk = k0 + ((kt + 1) << 5);
      gload_lds16(A  + (size_t)(m0 + srow)*Kfull + kk + skoff, (char*)&As[nxt][0][0] + wave*1024);
      gload_lds16(Bw + (size_t)(n0 + srow)*Kfull + kk + skoff, (char*)&Bs[nxt][0][0] + wave*1024);
    }
    bf16x8 af[2], bfm[2];
    #pragma unroll
    for (int f = 0; f < 2; ++f)
      af[f] = *(const bf16x8*)&As[cur][wm*32 + f*16 + ql][kbase];
    #pragma unroll
    for (int f = 0; f < 2; ++f)
      bfm[f] = *(const bf16x8*)&Bs[cur][wn*32 + f*16 + ql][kbase];
    #pragma unroll
    for (int fm = 0; fm < 2; ++fm)
      #pragma unroll
      for (int fn = 0; fn < 2; ++fn)
        acc[fm][fn] = __builtin_amdgcn_mfma_f32_16x16x32_bf16(af[fm], bfm[fn], acc[fm][fn], 0, 0, 0);
    __syncthreads();
  }

  #pragma unroll
  for (int fm = 0; fm < 2; ++fm) {
    const int rowb = m0 + wm*32 + fm*16 + hi*4;
    #pragma unroll
    for (int fn = 0; fn < 2; ++fn) {
      const int gcol = n0 + wn*32 + fn*16 + ql;
      float bv, scale = 1.0f;
      if (EPI == 0) {
        const int seg = gcol / 768;
        const int cw = gcol - seg*768;
        bv = (seg == 0) ? b0[cw] : ((seg == 1) ? b1[cw] : b2[cw]);
        if (seg == 0) scale = scaleQ;
      } else if (EPI == 1) {
        bv = (blockIdx.z == 0) ? b0[gcol] : 0.0f;
      } else {
        bv = b0[gcol];
      }
      f32x4 v = acc[fm][fn];
      #pragma unroll
      for (int j = 0; j < 4; ++j) {
        float val = (v[j] + bv) * scale;
        if (EPI == 0) {
          outB[(size_t)(rowb + j) * 2304 + gcol] = f2b(val);
        } else if (EPI == 1) {
          outF[(size_t)blockIdx.z * (Mm*768) + (size_t)(rowb + j) * 768 + gcol] = val;
        } else {
          float arg = 0.7978845608028654f * (val + 0.044715f * val * val * val);
          float e = __expf(2.0f * arg);
          float g = 0.5f * val * (2.0f - 2.0f / (e + 1.0f));
          outB[(size_t)(rowb + j) * 3072 + gcol] = f2b(g);
        }
      }
    }
  }
}

// ---------------- MFMA attention (qkv now bf16)
template<int PREBIAS>
__global__ __launch_bounds__(256) void attn2_kernel(
    const u16* __restrict__ qkv,         // [1536][2304] bf16 q|k|v (q pre-scaled)
    const u16* __restrict__ biasb,       // [B][H][N][N] bf16 (PREBIAS=1)
    const float* __restrict__ atb, const int* __restrict__ sp, const int* __restrict__ spT,
    const float* __restrict__ sp_emb, const float* __restrict__ sp_emb_rev,
    u16* __restrict__ ab)                // [1536][768] bf16
{
  __shared__ __align__(16) u16 Kt[384][32];   // [m][d(24)+pad]
  __shared__ __align__(16) u16 Vt[32][392];   // [d(24)+pad][m] transposed
  __shared__ __align__(16) u16 Qt[64][32];
  __shared__ __align__(16) u16 Pw[4][16][32]; // per-wave P chunk
  __shared__ float spc[512], sprc[512];
  const int bid = blockIdx.x;
  const int ntile = bid % 6;
  const int h = (bid / 6) % Hh;
  const int b = bid / (6 * Hh);
  const int t = threadIdx.x, lane = t & 63, wave = t >> 6;
  const int ql = lane & 15, hi = lane >> 4;

  for (int idx = t; idx < 384*6; idx += 256) {
    const int m = idx / 6, c = idx - m*6;
    const u16* base = qkv + ((size_t)m*Bb + b)*2304 + h*24 + c*4;
    uint2 kk = *(const uint2*)(base + 768);
    uint2 vv = *(const uint2*)(base + 1536);
    *(uint2*)&Kt[m][c*4] = kk;
    Vt[c*4+0][m] = (u16)(vv.x & 0xffffu); Vt[c*4+1][m] = (u16)(vv.x >> 16);
    Vt[c*4+2][m] = (u16)(vv.y & 0xffffu); Vt[c*4+3][m] = (u16)(vv.y >> 16);
  }
  for (int idx = t; idx < 384*2; idx += 256)           // K d-pad
    *(uint2*)&Kt[idx>>1][24 + (idx&1)*4] = make_uint2(0u, 0u);
  for (int idx = t; idx < 8*196; idx += 256)           // V^T d-pad rows
    *(unsigned*)((char*)&Vt[24][0] + idx*4) = 0u;
  for (int idx = t; idx < 64*6; idx += 256) {
    const int qr = idx / 6, c = idx - qr*6;
    const u16* base = qkv + ((size_t)(ntile*64 + qr)*Bb + b)*2304 + h*24 + c*4;
    *(uint2*)&Qt[qr][c*4] = *(const uint2*)base;
  }
  for (int idx = t; idx < 64*2; idx += 256)
    *(uint2*)&Qt[idx>>1][24 + (idx&1)*4] = make_uint2(0u, 0u);
  if (!PREBIAS) {
    for (int i = t; i < 512; i += 256) {
      spc[i]  = sp_emb[(size_t)i*Hh + h];
      sprc[i] = sp_emb_rev[(size_t)i*Hh + h];
    }
  }
  __syncthreads();

  const int q0 = ntile*64 + wave*16;
  const int q = q0 + ql;
  const bf16x8 qf = *(const bf16x8*)&Qt[wave*16 + ql][hi*8];

  f32x4 f[24];
  const u16* bp = biasb + (((size_t)b*Hh + h)*Nn + q)*Nn;
  const size_t crow = ((size_t)b*Nn + q)*Nn;
  #pragma unroll
  for (int tt = 0; tt < 24; ++tt) {
    bf16x8 kf = *(const bf16x8*)&Kt[tt*16 + ql][hi*8];
    f32x4 z = (f32x4){0.f,0.f,0.f,0.f};
    f32x4 s = __builtin_amdgcn_mfma_f32_16x16x32_bf16(kf, qf, z, 0, 0, 0);
    if (PREBIAS) {
      uint2 bb = *(const uint2*)(bp + tt*16 + hi*4);
      s[0] += b2f((u16)(bb.x & 0xffffu)); s[1] += b2f((u16)(bb.x >> 16));
      s[2] += b2f((u16)(bb.y & 0xffffu)); s[3] += b2f((u16)(bb.y >> 16));
    } else {
      const int off = tt*16 + hi*4;
      int4 s4 = *(const int4*)(sp + crow + off);
      int4 t4 = *(const int4*)(spT + crow + off);
      float4 a4 = *(const float4*)(atb + crow + off);
      s[0] += a4.x + spc[s4.x] + sprc[t4.x];
      s[1] += a4.y + spc[s4.y] + sprc[t4.y];
      s[2] += a4.z + spc[s4.z] + sprc[t4.z];
      s[3] += a4.w + spc[s4.w] + sprc[t4.w];
    }
    f[tt] = s;
  }

  float mx = -3.0e38f;
  #pragma unroll
  for (int tt = 0; tt < 24; ++tt)
    mx = fmaxf(mx, fmaxf(fmaxf(f[tt][0], f[tt][1]), fmaxf(f[tt][2], f[tt][3])));
  mx = fmaxf(mx, __shfl_xor(mx, 16, 64));
  mx = fmaxf(mx, __shfl_xor(mx, 32, 64));
  float sum = 0.f;
  #pragma unroll
  for (int tt = 0; tt < 24; ++tt) {
    #pragma unroll
    for (int j = 0; j < 4; ++j) { f[tt][j] = __expf(f[tt][j] - mx); sum += f[tt][j]; }
  }
  sum += __shfl_xor(sum, 16, 64);
  sum += __shfl_xor(sum, 32, 64);
  const float inv = 1.0f / sum;

  f32x4 o0 = (f32x4){0.f,0.f,0.f,0.f}, o1 = (f32x4){0.f,0.f,0.f,0.f};
  char* prow = (char*)&Pw[wave][ql][0];
  const int swz = (ql & 3) << 4;
  #pragma unroll
  for (int c = 0; c < 12; ++c) {
    unsigned w0 = pkcvt(f[2*c][0],   f[2*c][1]);
    unsigned w1 = pkcvt(f[2*c][2],   f[2*c][3]);
    unsigned w2 = pkcvt(f[2*c+1][0], f[2*c+1][1]);
    unsigned w3 = pkcvt(f[2*c+1][2], f[2*c+1][3]);
    *(unsigned*)(prow + (((hi*8)      ) ^ swz)) = w0;
    *(unsigned*)(prow + (((hi*8) +  4) ^ swz)) = w1;
    *(unsigned*)(prow + (((hi*8) + 32) ^ swz)) = w2;
    *(unsigned*)(prow + (((hi*8) + 36) ^ swz)) = w3;
    bf16x8 a = *(const bf16x8*)(prow + ((hi*16) ^ swz));
    bf16x8 v0 = *(const bf16x8*)&Vt[ql][c*32 + hi*8];
    bf16x8 v1 = *(const bf16x8*)&Vt[16 + ql][c*32 + hi*8];
    o0 = __builtin_amdgcn_mfma_f32_16x16x32_bf16(a, v0, o0, 0, 0, 0);
    o1 = __builtin_amdgcn_mfma_f32_16x16x32_bf16(a, v1, o1, 0, 0, 0);
  }

  #pragma unroll
  for (int j = 0; j < 4; ++j) {
    float invj = __shfl(inv, hi*4 + j, 64);
    const int qg = q0 + hi*4 + j;
    u16* orow = ab + ((size_t)qg*Bb + b)*Ee + h*24;
    orow[ql] = f2b(o0[j] * invj);
    if (ql < 8) orow[16 + ql] = f2b(o1[j] * invj);
  }
}

// ---------------- residual + LayerNorm, sums NP split-K partials
template<int NP>
__global__ __launch_bounds__(256) void ln_kernel(
    const float* __restrict__ xin, const float* __restrict__ delta,
    const float* __restrict__ gamma, const float* __restrict__ beta,
    float* __restrict__ xout, u16* __restrict__ xb)
{
  __shared__ float red[8];
  const int r = blockIdx.x, t = threadIdx.x;
  const size_t base = (size_t)r * Ee;
  float v[3];
  #pragma unroll
  for (int i = 0; i < 3; ++i) {
    int c = t + i*256;
    float d = xin[base + c];
    #pragma unroll
    for (int p = 0; p < NP; ++p) d += delta[(size_t)p*(Mm*768) + base + c];
    v[i] = d;
  }
  float s = v[0] + v[1] + v[2];
  #pragma unroll
  for (int off = 1; off < 64; off <<= 1) s += __shfl_xor(s, off, 64);
  if ((t & 63) == 0) red[t >> 6] = s;
  __syncthreads();
  const float mean = (red[0] + red[1] + red[2] + red[3]) * (1.0f / 768.0f);
  float qs = 0.f;
  #pragma unroll
  for (int i = 0; i < 3; ++i) { float d = v[i] - mean; qs += d * d; }
  #pragma unroll
  for (int off = 1; off < 64; off <<= 1) qs += __shfl_xor(qs, off, 64);
  if ((t & 63) == 0) red[4 + (t >> 6)] = qs;
  __syncthreads();
  const float var = (red[4] + red[5] + red[6] + red[7]) * (1.0f / 768.0f);
  const float rstd = rsqrtf(var + 1e-5f);
  #pragma unroll
  for (int i = 0; i < 3; ++i) {
    int c = t + i*256;
    float o = (v[i] - mean) * rstd * gamma[c] + beta[c];
    xout[base + c] = o;
    xb[base + c] = f2b(o);
  }
}

extern "C" void kernel_launch(void* const* d_in, const int* in_sizes, int n_in,
                              void* d_out, int out_size, void* d_ws, size_t ws_size,
                              hipStream_t stream) {
  const int*   node_type  = (const int*)d_in[0];
  const float* nif        = (const float*)d_in[1];
  const int*   in_deg     = (const int*)d_in[2];
  const int*   out_deg    = (const int*)d_in[3];
  const float* atb        = (const float*)d_in[4];
  const int*   sp         = (const int*)d_in[5];
  const float* node_emb   = (const float*)d_in[6];
  const float* ind_emb    = (const float*)d_in[7];
  const float* outd_emb   = (const float*)d_in[8];
  const float* sp_emb     = (const float*)d_in[9];
  const float* sp_emb_rev = (const float*)d_in[10];
  const float* Wq = (const float*)d_in[11]; const float* bq = (const float*)d_in[12];
  const float* Wk = (const float*)d_in[13]; const float* bk = (const float*)d_in[14];
  const float* Wv = (const float*)d_in[15]; const float* bv = (const float*)d_in[16];
  const float* Wo = (const float*)d_in[17]; const float* bo = (const float*)d_in[18];
  const float* W1 = (const float*)d_in[19]; const float* b1 = (const float*)d_in[20];
  const float* W2 = (const float*)d_in[21]; const float* b2 = (const float*)d_in[22];
  const float* ln1s = (const float*)d_in[23]; const float* ln1b = (const float*)d_in[24];
  const float* ln2s = (const float*)d_in[25]; const float* ln2b = (const float*)d_in[26];

  char* ws = (char*)d_ws;
  float* x      = (float*)(ws);                    //  4,718,592
  u16*   xb     = (u16*)(ws +  4718592);           //  2,359,296
  u16*   qkvb16 = (u16*)(ws +  7077888);           //  7,077,888
  u16*   abuf   = (u16*)(ws + 14155776);           //  2,359,296
  u16*   hb     = (u16*)(ws + 16515072);           //  9,437,184
  float* obufP  = (float*)(ws + 25952256);         // 18,874,368 (4 partials)
  int*   spTb   = (int*)(ws + 44826624);           //  2,359,296
  u16*   biasb  = (u16*)(ws + 47185920);           // 37,748,736 -> 84,934,656
  // weights after biasb (tier>=1) or in its place (tier0)
  const bool useBias = ws_size >= 99090432ull;
  const bool allW    = ws_size >= 254803968ull;
  u16* wTall = (u16*)(ws + (useBias ? 84934656 : 47185920));
  const unsigned LSLOT = 7077888u;   // elements per layer slot

  embed_kernel<<<Mm, 256, 0, stream>>>(node_type, nif, in_deg, out_deg,
                                       node_emb, ind_emb, outd_emb, x, xb);
  spT_kernel<<<dim3(12, 12, 4), dim3(32, 8), 0, stream>>>(sp, spTb);
  if (useBias)
    bias_pre_kernel<<<dim3(24, 4, 4), 256, 0, stream>>>(atb, sp, spTb, sp_emb, sp_emb_rev, biasb);
  if (allW)
    wconv_kernel<<<dim3(6912, 12), dim3(32, 8), 0, stream>>>(Wq, Wk, Wv, Wo, W1, W2,
                                                             0, wTall, LSLOT);

  const float scaleQ = 0.2041241452319315f;  // 24^-0.5

  for (int l = 0; l < Ll; ++l) {
    const float *bql = bq + (size_t)l*Ee, *bkl = bk + (size_t)l*Ee, *bvl = bv + (size_t)l*Ee;
    const float *bol = bo + (size_t)l*Ee;
    const float *b1l = b1 + (size_t)l*Ff, *b2l = b2 + (size_t)l*Ee;

    if (!allW)
      wconv_kernel<<<dim3(6912, 1), dim3(32, 8), 0, stream>>>(Wq, Wk, Wv, Wo, W1, W2,
                                                              l, wTall, 0u);
    u16* slot = wTall + (size_t)(allW ? l : 0) * LSLOT;
    const u16* qkvT = slot;
    const u16* woT  = slot + 1769472;
    const u16* w1T  = slot + 2359296;
    const u16* w2T  = slot + 4718592;

    // QKV: [1536,768] @ [2304,768]^T -> bf16 [1536][2304]
    gemm3_kernel<0><<<dim3(24, 36), 256, 0, stream>>>(xb, qkvT, bql, bkl, bvl,
                                                      768, 768, scaleQ, nullptr, qkvb16);
    if (useBias)
      attn2_kernel<1><<<768, 256, 0, stream>>>(qkvb16, biasb, atb, sp, spTb,
                                               sp_emb, sp_emb_rev, abuf);
    else
      attn2_kernel<0><<<768, 256, 0, stream>>>(qkvb16, nullptr, atb, sp, spTb,
                                               sp_emb, sp_emb_rev, abuf);
    // O-proj: split-K 2 -> partials
    gemm3_kernel<1><<<dim3(24, 12, 2), 256, 0, stream>>>(abuf, woT, bol, bol, bol,
                                                         768, 384, 1.0f, obufP, nullptr);
    ln_kernel<2><<<Mm, 256, 0, stream>>>(x, obufP, ln1s + (size_t)l*Ee, ln1b + (size_t)l*Ee, x, xb);
    // FFN1 + gelu -> bf16 hidden
    gemm3_kernel<2><<<dim3(24, 48), 256, 0, stream>>>(xb, w1T, b1l, b1l, b1l,
                                                      768, 768, 1.0f, nullptr, hb);
    // FFN2: split-K 4 -> partials
    gemm3_kernel<1><<<dim3(24, 12, 4), 256, 0, stream>>>(hb, w2T, b2l, b2l, b2l,
                                                         3072, 768, 1.0f, obufP, nullptr);
    float* xdst = (l == Ll - 1) ? (float*)d_out : x;
    ln_kernel<4><<<Mm, 256, 0, stream>>>(x, obufP, ln2s + (size_t)l*Ee, ln2b + (size_t)l*Ee, xdst, xb);
  }
}

// Round 4
// 1408.989 us; speedup vs baseline: 3.2325x; 1.1314x over previous
//
#include <hip/hip_runtime.h>
#include <hip/hip_bf16.h>

#define Bb 4
#define Nn 384
#define Ee 768
#define Hh 32
#define Ff 3072
#define Ll 12
#define Ss 512
#define Mm (Nn*Bb)   // 1536 tokens

typedef __attribute__((ext_vector_type(8))) short bf16x8;
typedef __attribute__((ext_vector_type(4))) float f32x4;
typedef unsigned short u16;

__device__ __forceinline__ u16 f2b(float f) {
  union { float f; unsigned int i; } c; c.f = f;
  unsigned int x = c.i;
  return (u16)((x + 0x7fffu + ((x >> 16) & 1u)) >> 16); // RNE
}
__device__ __forceinline__ float b2f(u16 u) {
  union { unsigned int i; float f; } c; c.i = ((unsigned int)u) << 16; return c.f;
}
__device__ __forceinline__ unsigned pkcvt(float lo, float hi) {
  unsigned r;
  asm("v_cvt_pk_bf16_f32 %0, %1, %2" : "=v"(r) : "v"(lo), "v"(hi));
  return r;
}
__device__ __forceinline__ void gload_lds16(const void* g, void* l) {
  __builtin_amdgcn_global_load_lds((__attribute__((address_space(1))) void*)(g),
                                   (__attribute__((address_space(3))) void*)(l), 16, 0, 0);
}

// ---------------- embedding
__global__ __launch_bounds__(256) void embed_kernel(
    const int* __restrict__ node_type, const float* __restrict__ nif,
    const int* __restrict__ in_deg, const int* __restrict__ out_deg,
    const float* __restrict__ node_emb, const float* __restrict__ ind_emb,
    const float* __restrict__ outd_emb,
    float* __restrict__ x, u16* __restrict__ xb)
{
  const int r = blockIdx.x;           // r = n*B + b
  const int n = r / Bb, b = r % Bb;
  const int nt  = node_type[b*Nn + n];
  const int idg = in_deg[b*Nn + n];
  const int odg = out_deg[b*Nn + n];
  for (int c = threadIdx.x; c < Ee; c += 256) {
    float val = node_emb[(size_t)nt*Ee + c] + ind_emb[(size_t)idg*Ee + c]
              + outd_emb[(size_t)odg*Ee + c] + nif[((size_t)b*Nn + n)*Ee + c];
    x[(size_t)r*Ee + c] = val;
    xb[(size_t)r*Ee + c] = f2b(val);
  }
}

// ---------------- spatial_pos transpose
__global__ void spT_kernel(const int* __restrict__ sp, int* __restrict__ spT)
{
  __shared__ int tile[32][33];
  const int b = blockIdx.z;
  const int n0 = blockIdx.y * 32, m0 = blockIdx.x * 32;
  const int tx = threadIdx.x, ty = threadIdx.y;
  for (int i = ty; i < 32; i += 8)
    tile[i][tx] = sp[((size_t)b*Nn + n0 + i)*Nn + m0 + tx];
  __syncthreads();
  for (int i = ty; i < 32; i += 8)
    spT[((size_t)b*Nn + m0 + i)*Nn + n0 + tx] = tile[tx][i];
}

// ---------------- bias precompute into MFMA-fragment chunk layout:
// flat[(((b*H+h)*24 + bx)*24 + tt)*256 + hi*64 + ql*4 + j]
//   = bias(b, h, q = bx*16 + ql, m = tt*16 + hi*4 + j)
__global__ __launch_bounds__(256) void bias_pre_kernel(
    const float* __restrict__ atb, const int* __restrict__ sp, const int* __restrict__ spT,
    const float* __restrict__ sp_emb, const float* __restrict__ sp_emb_rev,
    u16* __restrict__ biasb)
{
  __shared__ float spc[512], sprc[512];
  const int bx = blockIdx.x, h = blockIdx.y, b = blockIdx.z;
  const int t = threadIdx.x;
  for (int i = t; i < 512; i += 256) {
    spc[i]  = sp_emb[(size_t)i*Hh + h];
    sprc[i] = sp_emb_rev[(size_t)i*Hh + h];
  }
  __syncthreads();
  const int q = bx*16 + ((t >> 2) & 15);
  const size_t rowb = ((size_t)b*Nn + q)*Nn;
  u16* outb = biasb + (((size_t)(b*Hh + h)*24 + bx)*24)*256 + t;
  const int mbase = ((t >> 6) << 2) + (t & 3);
  for (int tt = 0; tt < 24; ++tt) {
    const int m = tt*16 + mbase;
    float v = atb[rowb + m] + spc[sp[rowb + m]] + sprc[spT[rowb + m]];
    outb[tt*256] = f2b(v);
  }
}

// ---------------- weight transpose+convert (vectorized): src f32 [Ks][Ns] -> dst bf16 [Ns][Ks]
__global__ __launch_bounds__(256) void wconv_kernel(
    const float* __restrict__ Wq, const float* __restrict__ Wk, const float* __restrict__ Wv,
    const float* __restrict__ Wo, const float* __restrict__ W1, const float* __restrict__ W2,
    int layer0, u16* __restrict__ wTall, unsigned slotStride)
{
  __shared__ float tile[64][68];
  const int layer = layer0 + blockIdx.y;
  u16* slot = wTall + (size_t)blockIdx.y * slotStride;
  int tid = blockIdx.x;
  const float* src; u16* dst; int Ns, Ks;
  if (tid < 432)       { int seg = tid / 144; tid -= seg*144;
                         src = (seg==0?Wq:(seg==1?Wk:Wv)) + (size_t)layer*Ee*Ee;
                         dst = slot + (size_t)seg*589824; Ns = 768; Ks = 768; }
  else if (tid < 576)  { tid -= 432; src = Wo + (size_t)layer*Ee*Ee; dst = slot + 1769472; Ns = 768;  Ks = 768; }
  else if (tid < 1152) { tid -= 576; src = W1 + (size_t)layer*Ee*Ff; dst = slot + 2359296; Ns = 3072; Ks = 768; }
  else                 { tid -= 1152; src = W2 + (size_t)layer*Ff*Ee; dst = slot + 4718592; Ns = 768; Ks = 3072; }
  const int tc = Ns >> 6;
  const int tk = tid / tc, tn = tid % tc;
  const int t = threadIdx.x;
  // load 64x64 f32 tile: 1024 float4, 4 per thread, 256B/wave row segments
  #pragma unroll
  for (int i = 0; i < 4; ++i) {
    const int id = t + i*256;
    const int r = id >> 4, c = (id & 15) << 2;
    *(float4*)&tile[r][c] = *(const float4*)(src + (size_t)(tk*64 + r)*Ns + tn*64 + c);
  }
  __syncthreads();
  // write: 512 chunks of 8 k-values, 2 per thread, 128B contiguous per n-row
  #pragma unroll
  for (int i = 0; i < 2; ++i) {
    const int ch = t + i*256;
    const int n = ch >> 3, kc = (ch & 7) << 3;
    uint4 u;
    u.x = pkcvt(tile[kc+0][n], tile[kc+1][n]);
    u.y = pkcvt(tile[kc+2][n], tile[kc+3][n]);
    u.z = pkcvt(tile[kc+4][n], tile[kc+5][n]);
    u.w = pkcvt(tile[kc+6][n], tile[kc+7][n]);
    *(uint4*)(dst + (size_t)(tn*64 + n)*Ks + tk*64 + kc) = u;
  }
}

// ---------------- 64x64-tile GEMM, BK=64, counted-vmcnt 2-barrier pipeline, XCD-swizzled
// LDS rows are 128B; source is pre-swizzled (slot ^= row&7) so swizzled ds_reads recover
// the linear layout (rule #21: linear dest + inverse-swz source + swz read).
// EPI 0: qkv fused bias (Q scaled) -> bf16 out ld 2304
// EPI 1: f32 partial out ld 768 (bias only on z==0)
// EPI 2: gelu -> bf16 out ld 3072
template<int EPI>
__global__ __launch_bounds__(256) void gemm3_kernel(
    const u16* __restrict__ A, const u16* __restrict__ Bw,
    const float* __restrict__ b0, const float* __restrict__ b1, const float* __restrict__ b2,
    int Kfull, int Kc, float scaleQ,
    float* __restrict__ outF, u16* __restrict__ outB)
{
  __shared__ __align__(16) u16 As[2][64][64];
  __shared__ __align__(16) u16 Bs[2][64][64];
  const int t = threadIdx.x, lane = t & 63, wave = t >> 6;
  int bx = blockIdx.x, by = blockIdx.y;
  { // XCD swizzle (xy grid always divisible by 8)
    const int gx = gridDim.x;
    const int nwg = gx * gridDim.y;
    const int bid = bx + gx * by;
    const int cpx = nwg >> 3;
    const int s = (bid & 7) * cpx + (bid >> 3);
    bx = s % gx; by = s / gx;
  }
  const int m0 = bx * 64, n0 = by * 64;
  const int k0 = blockIdx.z * Kc;
  const int wm = wave >> 1, wn = wave & 1;
  const int ql = lane & 15, hi = lane >> 4;
  const int nk = Kc >> 6;
  // staging map: thread t covers rows sr and sr+32, 16B slot (t&7), source slot XOR'd
  const int sr = t >> 3;
  const int sslot = (t & 7) ^ (sr & 7);
  const size_t aoff = (size_t)(m0 + sr)*Kfull + k0 + (sslot << 3);
  const size_t boff = (size_t)(n0 + sr)*Kfull + k0 + (sslot << 3);
  const size_t rstep = (size_t)32 * Kfull;

  f32x4 acc[2][2];
  #pragma unroll
  for (int a = 0; a < 2; ++a)
    #pragma unroll
    for (int c = 0; c < 2; ++c) acc[a][c] = (f32x4){0.f,0.f,0.f,0.f};

  // prologue: issue tile 0 (no wait — first loop iteration's vmcnt(4)+B1 covers it)
  gload_lds16(A + aoff,         (char*)&As[0][0][0] + t*16);
  gload_lds16(A + aoff + rstep, (char*)&As[0][0][0] + 4096 + t*16);
  gload_lds16(Bw + boff,         (char*)&Bs[0][0][0] + t*16);
  gload_lds16(Bw + boff + rstep, (char*)&Bs[0][0][0] + 4096 + t*16);

  for (int kt = 0; kt < nk; ++kt) {
    const int cur = kt & 1, nxt = cur ^ 1;
    const bool pre = (kt + 1 < nk);
    if (pre) {
      const size_t kk = (size_t)(kt + 1) << 6;
      gload_lds16(A + aoff + kk,         (char*)&As[nxt][0][0] + t*16);
      gload_lds16(A + aoff + kk + rstep, (char*)&As[nxt][0][0] + 4096 + t*16);
      gload_lds16(Bw + boff + kk,         (char*)&Bs[nxt][0][0] + t*16);
      gload_lds16(Bw + boff + kk + rstep, (char*)&Bs[nxt][0][0] + 4096 + t*16);
      asm volatile("s_waitcnt vmcnt(4)" ::: "memory");   // tile kt done; kt+1 stays in flight
    } else {
      asm volatile("s_waitcnt vmcnt(0)" ::: "memory");
    }
    __builtin_amdgcn_s_barrier();            // B1: all waves' tile-kt loads landed
    __builtin_amdgcn_sched_barrier(0);

    const char* aBase = (const char*)&As[cur][0][0];
    const char* bBase = (const char*)&Bs[cur][0][0];
    bf16x8 af[2][2], bf[2][2];
    #pragma unroll
    for (int f = 0; f < 2; ++f)
      #pragma unroll
      for (int ks = 0; ks < 2; ++ks) {
        const int row = wm*32 + f*16 + ql;
        af[f][ks] = *(const bf16x8*)(aBase + row*128 + ((((ks<<2)+hi) ^ (ql&7)) << 4));
      }
    #pragma unroll
    for (int f = 0; f < 2; ++f)
      #pragma unroll
      for (int ks = 0; ks < 2; ++ks) {
        const int row = wn*32 + f*16 + ql;
        bf[f][ks] = *(const bf16x8*)(bBase + row*128 + ((((ks<<2)+hi) ^ (ql&7)) << 4));
      }
    #pragma unroll
    for (int ks = 0; ks < 2; ++ks)
      #pragma unroll
      for (int fm = 0; fm < 2; ++fm)
        #pragma unroll
        for (int fn = 0; fn < 2; ++fn)
          acc[fm][fn] = __builtin_amdgcn_mfma_f32_16x16x32_bf16(af[fm][ks], bf[fn][ks], acc[fm][fn], 0, 0, 0);
    if (pre) {
      __builtin_amdgcn_sched_barrier(0);
      __builtin_amdgcn_s_barrier();          // B2: reads of cur drained -> next issue may overwrite
    }
  }

  #pragma unroll
  for (int fm = 0; fm < 2; ++fm) {
    const int rowb = m0 + wm*32 + fm*16 + hi*4;
    #pragma unroll
    for (int fn = 0; fn < 2; ++fn) {
      const int gcol = n0 + wn*32 + fn*16 + ql;
      float bv, scale = 1.0f;
      if (EPI == 0) {
        const int seg = gcol / 768;
        const int cw = gcol - seg*768;
        bv = (seg == 0) ? b0[cw] : ((seg == 1) ? b1[cw] : b2[cw]);
        if (seg == 0) scale = scaleQ;
      } else if (EPI == 1) {
        bv = (blockIdx.z == 0) ? b0[gcol] : 0.0f;
      } else {
        bv = b0[gcol];
      }
      f32x4 v = acc[fm][fn];
      #pragma unroll
      for (int j = 0; j < 4; ++j) {
        float val = (v[j] + bv) * scale;
        if (EPI == 0) {
          outB[(size_t)(rowb + j) * 2304 + gcol] = f2b(val);
        } else if (EPI == 1) {
          outF[(size_t)blockIdx.z * (Mm*768) + (size_t)(rowb + j) * 768 + gcol] = val;
        } else {
          float arg = 0.7978845608028654f * (val + 0.044715f * val * val * val);
          float e = __expf(2.0f * arg);
          float g = 0.5f * val * (2.0f - 2.0f / (e + 1.0f));
          outB[(size_t)(rowb + j) * 3072 + gcol] = f2b(g);
        }
      }
    }
  }
}

// ---------------- MFMA attention (qkv bf16; bias in chunk layout when PREBIAS=1)
template<int PREBIAS>
__global__ __launch_bounds__(256) void attn2_kernel(
    const u16* __restrict__ qkv,         // [1536][2304] bf16 q|k|v (q pre-scaled)
    const u16* __restrict__ biasb,       // chunk layout (PREBIAS=1)
    const float* __restrict__ atb, const int* __restrict__ sp, const int* __restrict__ spT,
    const float* __restrict__ sp_emb, const float* __restrict__ sp_emb_rev,
    u16* __restrict__ ab)                // [1536][768] bf16
{
  __shared__ __align__(16) u16 Kt[384][32];   // [m][d(24)+pad]
  __shared__ __align__(16) u16 Vt[32][392];   // [d(24)+pad][m] transposed
  __shared__ __align__(16) u16 Qt[64][32];
  __shared__ __align__(16) u16 Pw[4][16][32]; // per-wave P chunk
  __shared__ float spc[512], sprc[512];
  const int bid = blockIdx.x;
  const int ntile = bid % 6;
  const int h = (bid / 6) % Hh;
  const int b = bid / (6 * Hh);
  const int t = threadIdx.x, lane = t & 63, wave = t >> 6;
  const int ql = lane & 15, hi = lane >> 4;

  for (int idx = t; idx < 384*6; idx += 256) {
    const int m = idx / 6, c = idx - m*6;
    const u16* base = qkv + ((size_t)m*Bb + b)*2304 + h*24 + c*4;
    uint2 kk = *(const uint2*)(base + 768);
    uint2 vv = *(const uint2*)(base + 1536);
    *(uint2*)&Kt[m][c*4] = kk;
    Vt[c*4+0][m] = (u16)(vv.x & 0xffffu); Vt[c*4+1][m] = (u16)(vv.x >> 16);
    Vt[c*4+2][m] = (u16)(vv.y & 0xffffu); Vt[c*4+3][m] = (u16)(vv.y >> 16);
  }
  for (int idx = t; idx < 384*2; idx += 256)           // K d-pad
    *(uint2*)&Kt[idx>>1][24 + (idx&1)*4] = make_uint2(0u, 0u);
  for (int idx = t; idx < 8*196; idx += 256)           // V^T d-pad rows
    *(unsigned*)((char*)&Vt[24][0] + idx*4) = 0u;
  for (int idx = t; idx < 64*6; idx += 256) {
    const int qr = idx / 6, c = idx - qr*6;
    const u16* base = qkv + ((size_t)(ntile*64 + qr)*Bb + b)*2304 + h*24 + c*4;
    *(uint2*)&Qt[qr][c*4] = *(const uint2*)base;
  }
  for (int idx = t; idx < 64*2; idx += 256)
    *(uint2*)&Qt[idx>>1][24 + (idx&1)*4] = make_uint2(0u, 0u);
  if (!PREBIAS) {
    for (int i = t; i < 512; i += 256) {
      spc[i]  = sp_emb[(size_t)i*Hh + h];
      sprc[i] = sp_emb_rev[(size_t)i*Hh + h];
    }
  }
  __syncthreads();

  const int q0 = ntile*64 + wave*16;
  const int q = q0 + ql;
  const bf16x8 qf = *(const bf16x8*)&Qt[wave*16 + ql][hi*8];

  f32x4 f[24];
  const u16* bp = biasb + (((size_t)(b*Hh + h)*24 + ntile*4 + wave)*24)*256 + lane*4;
  const size_t crow = ((size_t)b*Nn + q)*Nn;
  #pragma unroll
  for (int tt = 0; tt < 24; ++tt) {
    bf16x8 kf = *(const bf16x8*)&Kt[tt*16 + ql][hi*8];
    f32x4 z = (f32x4){0.f,0.f,0.f,0.f};
    f32x4 s = __builtin_amdgcn_mfma_f32_16x16x32_bf16(kf, qf, z, 0, 0, 0);
    if (PREBIAS) {
      uint2 bb = *(const uint2*)(bp + tt*256);
      s[0] += b2f((u16)(bb.x & 0xffffu)); s[1] += b2f((u16)(bb.x >> 16));
      s[2] += b2f((u16)(bb.y & 0xffffu)); s[3] += b2f((u16)(bb.y >> 16));
    } else {
      const int off = tt*16 + hi*4;
      int4 s4 = *(const int4*)(sp + crow + off);
      int4 t4 = *(const int4*)(spT + crow + off);
      float4 a4 = *(const float4*)(atb + crow + off);
      s[0] += a4.x + spc[s4.x] + sprc[t4.x];
      s[1] += a4.y + spc[s4.y] + sprc[t4.y];
      s[2] += a4.z + spc[s4.z] + sprc[t4.z];
      s[3] += a4.w + spc[s4.w] + sprc[t4.w];
    }
    f[tt] = s;
  }

  float mx = -3.0e38f;
  #pragma unroll
  for (int tt = 0; tt < 24; ++tt)
    mx = fmaxf(mx, fmaxf(fmaxf(f[tt][0], f[tt][1]), fmaxf(f[tt][2], f[tt][3])));
  mx = fmaxf(mx, __shfl_xor(mx, 16, 64));
  mx = fmaxf(mx, __shfl_xor(mx, 32, 64));
  float sum = 0.f;
  #pragma unroll
  for (int tt = 0; tt < 24; ++tt) {
    #pragma unroll
    for (int j = 0; j < 4; ++j) { f[tt][j] = __expf(f[tt][j] - mx); sum += f[tt][j]; }
  }
  sum += __shfl_xor(sum, 16, 64);
  sum += __shfl_xor(sum, 32, 64);
  const float inv = 1.0f / sum;

  f32x4 o0 = (f32x4){0.f,0.f,0.f,0.f}, o1 = (f32x4){0.f,0.f,0.f,0.f};
  char* prow = (char*)&Pw[wave][ql][0];
  const int swz = (ql & 3) << 4;
  #pragma unroll
  for (int c = 0; c < 12; ++c) {
    unsigned w0 = pkcvt(f[2*c][0],   f[2*c][1]);
    unsigned w1 = pkcvt(f[2*c][2],   f[2*c][3]);
    unsigned w2 = pkcvt(f[2*c+1][0], f[2*c+1][1]);
    unsigned w3 = pkcvt(f[2*c+1][2], f[2*c+1][3]);
    *(unsigned*)(prow + (((hi*8)      ) ^ swz)) = w0;
    *(unsigned*)(prow + (((hi*8) +  4) ^ swz)) = w1;
    *(unsigned*)(prow + (((hi*8) + 32) ^ swz)) = w2;
    *(unsigned*)(prow + (((hi*8) + 36) ^ swz)) = w3;
    bf16x8 a = *(const bf16x8*)(prow + ((hi*16) ^ swz));
    bf16x8 v0 = *(const bf16x8*)&Vt[ql][c*32 + hi*8];
    bf16x8 v1 = *(const bf16x8*)&Vt[16 + ql][c*32 + hi*8];
    o0 = __builtin_amdgcn_mfma_f32_16x16x32_bf16(a, v0, o0, 0, 0, 0);
    o1 = __builtin_amdgcn_mfma_f32_16x16x32_bf16(a, v1, o1, 0, 0, 0);
  }

  #pragma unroll
  for (int j = 0; j < 4; ++j) {
    float invj = __shfl(inv, hi*4 + j, 64);
    const int qg = q0 + hi*4 + j;
    u16* orow = ab + ((size_t)qg*Bb + b)*Ee + h*24;
    orow[ql] = f2b(o0[j] * invj);
    if (ql < 8) orow[16 + ql] = f2b(o1[j] * invj);
  }
}

// ---------------- residual + LayerNorm, sums NP split-K partials
template<int NP>
__global__ __launch_bounds__(256) void ln_kernel(
    const float* __restrict__ xin, const float* __restrict__ delta,
    const float* __restrict__ gamma, const float* __restrict__ beta,
    float* __restrict__ xout, u16* __restrict__ xb)
{
  __shared__ float red[8];
  const int r = blockIdx.x, t = threadIdx.x;
  const size_t base = (size_t)r * Ee;
  float v[3];
  #pragma unroll
  for (int i = 0; i < 3; ++i) {
    int c = t + i*256;
    float d = xin[base + c];
    #pragma unroll
    for (int p = 0; p < NP; ++p) d += delta[(size_t)p*(Mm*768) + base + c];
    v[i] = d;
  }
  float s = v[0] + v[1] + v[2];
  #pragma unroll
  for (int off = 1; off < 64; off <<= 1) s += __shfl_xor(s, off, 64);
  if ((t & 63) == 0) red[t >> 6] = s;
  __syncthreads();
  const float mean = (red[0] + red[1] + red[2] + red[3]) * (1.0f / 768.0f);
  float qs = 0.f;
  #pragma unroll
  for (int i = 0; i < 3; ++i) { float d = v[i] - mean; qs += d * d; }
  #pragma unroll
  for (int off = 1; off < 64; off <<= 1) qs += __shfl_xor(qs, off, 64);
  if ((t & 63) == 0) red[4 + (t >> 6)] = qs;
  __syncthreads();
  const float var = (red[4] + red[5] + red[6] + red[7]) * (1.0f / 768.0f);
  const float rstd = rsqrtf(var + 1e-5f);
  #pragma unroll
  for (int i = 0; i < 3; ++i) {
    int c = t + i*256;
    float o = (v[i] - mean) * rstd * gamma[c] + beta[c];
    xout[base + c] = o;
    xb[base + c] = f2b(o);
  }
}

extern "C" void kernel_launch(void* const* d_in, const int* in_sizes, int n_in,
                              void* d_out, int out_size, void* d_ws, size_t ws_size,
                              hipStream_t stream) {
  const int*   node_type  = (const int*)d_in[0];
  const float* nif        = (const float*)d_in[1];
  const int*   in_deg     = (const int*)d_in[2];
  const int*   out_deg    = (const int*)d_in[3];
  const float* atb        = (const float*)d_in[4];
  const int*   sp         = (const int*)d_in[5];
  const float* node_emb   = (const float*)d_in[6];
  const float* ind_emb    = (const float*)d_in[7];
  const float* outd_emb   = (const float*)d_in[8];
  const float* sp_emb     = (const float*)d_in[9];
  const float* sp_emb_rev = (const float*)d_in[10];
  const float* Wq = (const float*)d_in[11]; const float* bq = (const float*)d_in[12];
  const float* Wk = (const float*)d_in[13]; const float* bk = (const float*)d_in[14];
  const float* Wv = (const float*)d_in[15]; const float* bv = (const float*)d_in[16];
  const float* Wo = (const float*)d_in[17]; const float* bo = (const float*)d_in[18];
  const float* W1 = (const float*)d_in[19]; const float* b1 = (const float*)d_in[20];
  const float* W2 = (const float*)d_in[21]; const float* b2 = (const float*)d_in[22];
  const float* ln1s = (const float*)d_in[23]; const float* ln1b = (const float*)d_in[24];
  const float* ln2s = (const float*)d_in[25]; const float* ln2b = (const float*)d_in[26];

  char* ws = (char*)d_ws;
  float* x      = (float*)(ws);                    //  4,718,592
  u16*   xb     = (u16*)(ws +  4718592);           //  2,359,296
  u16*   qkvb16 = (u16*)(ws +  7077888);           //  7,077,888
  u16*   abuf   = (u16*)(ws + 14155776);           //  2,359,296
  u16*   hb     = (u16*)(ws + 16515072);           //  9,437,184
  float* obufP  = (float*)(ws + 25952256);         // 18,874,368 (4 partials)
  int*   spTb   = (int*)(ws + 44826624);           //  2,359,296
  u16*   biasb  = (u16*)(ws + 47185920);           // 37,748,736 -> 84,934,656
  const bool useBias = ws_size >= 99090432ull;
  const bool allW    = ws_size >= 254803968ull;
  u16* wTall = (u16*)(ws + (useBias ? 84934656 : 47185920));
  const unsigned LSLOT = 7077888u;   // u16 elements per layer slot

  embed_kernel<<<Mm, 256, 0, stream>>>(node_type, nif, in_deg, out_deg,
                                       node_emb, ind_emb, outd_emb, x, xb);
  spT_kernel<<<dim3(12, 12, 4), dim3(32, 8), 0, stream>>>(sp, spTb);
  if (useBias)
    bias_pre_kernel<<<dim3(24, 32, 4), 256, 0, stream>>>(atb, sp, spTb, sp_emb, sp_emb_rev, biasb);
  if (allW)
    wconv_kernel<<<dim3(1728, 12), 256, 0, stream>>>(Wq, Wk, Wv, Wo, W1, W2,
                                                     0, wTall, LSLOT);

  const float scaleQ = 0.2041241452319315f;  // 24^-0.5

  for (int l = 0; l < Ll; ++l) {
    const float *bql = bq + (size_t)l*Ee, *bkl = bk + (size_t)l*Ee, *bvl = bv + (size_t)l*Ee;
    const float *bol = bo + (size_t)l*Ee;
    const float *b1l = b1 + (size_t)l*Ff, *b2l = b2 + (size_t)l*Ee;

    if (!allW)
      wconv_kernel<<<dim3(1728, 1), 256, 0, stream>>>(Wq, Wk, Wv, Wo, W1, W2,
                                                      l, wTall, 0u);
    u16* slot = wTall + (size_t)(allW ? l : 0) * LSLOT;
    const u16* qkvT = slot;
    const u16* woT  = slot + 1769472;
    const u16* w1T  = slot + 2359296;
    const u16* w2T  = slot + 4718592;

    // QKV: [1536,768] @ [2304,768]^T -> bf16 [1536][2304]
    gemm3_kernel<0><<<dim3(24, 36), 256, 0, stream>>>(xb, qkvT, bql, bkl, bvl,
                                                      768, 768, scaleQ, nullptr, qkvb16);
    if (useBias)
      attn2_kernel<1><<<768, 256, 0, stream>>>(qkvb16, biasb, atb, sp, spTb,
                                               sp_emb, sp_emb_rev, abuf);
    else
      attn2_kernel<0><<<768, 256, 0, stream>>>(qkvb16, nullptr, atb, sp, spTb,
                                               sp_emb, sp_emb_rev, abuf);
    // O-proj: split-K 2 -> partials
    gemm3_kernel<1><<<dim3(24, 12, 2), 256, 0, stream>>>(abuf, woT, bol, bol, bol,
                                                         768, 384, 1.0f, obufP, nullptr);
    ln_kernel<2><<<Mm, 256, 0, stream>>>(x, obufP, ln1s + (size_t)l*Ee, ln1b + (size_t)l*Ee, x, xb);
    // FFN1 + gelu -> bf16 hidden
    gemm3_kernel<2><<<dim3(24, 48), 256, 0, stream>>>(xb, w1T, b1l, b1l, b1l,
                                                      768, 768, 1.0f, nullptr, hb);
    // FFN2: split-K 4 -> partials
    gemm3_kernel<1><<<dim3(24, 12, 4), 256, 0, stream>>>(hb, w2T, b2l, b2l, b2l,
                                                         3072, 768, 1.0f, obufP, nullptr);
    float* xdst = (l == Ll - 1) ? (float*)d_out : x;
    ln_kernel<4><<<Mm, 256, 0, stream>>>(x, obufP, ln2s + (size_t)l*Ee, ln2b + (size_t)l*Ee, xdst, xb);
  }
}

// Round 5
// 1346.584 us; speedup vs baseline: 3.3824x; 1.0463x over previous
//
#include <hip/hip_runtime.h>
#include <hip/hip_bf16.h>

#define Bb 4
#define Nn 384
#define Ee 768
#define Hh 32
#define Ff 3072
#define Ll 12
#define Ss 512
#define Mm (Nn*Bb)   // 1536 tokens

typedef __attribute__((ext_vector_type(8))) short bf16x8;
typedef __attribute__((ext_vector_type(4))) float f32x4;
typedef unsigned short u16;

__device__ __forceinline__ u16 f2b(float f) {
  union { float f; unsigned int i; } c; c.f = f;
  unsigned int x = c.i;
  return (u16)((x + 0x7fffu + ((x >> 16) & 1u)) >> 16); // RNE
}
__device__ __forceinline__ float b2f(u16 u) {
  union { unsigned int i; float f; } c; c.i = ((unsigned int)u) << 16; return c.f;
}
__device__ __forceinline__ unsigned pkcvt(float lo, float hi) {
  unsigned r;
  asm("v_cvt_pk_bf16_f32 %0, %1, %2" : "=v"(r) : "v"(lo), "v"(hi));
  return r;
}
__device__ __forceinline__ void gload_lds16(const void* g, void* l) {
  __builtin_amdgcn_global_load_lds((__attribute__((address_space(1))) void*)(g),
                                   (__attribute__((address_space(3))) void*)(l), 16, 0, 0);
}

// ---------------- embedding
__global__ __launch_bounds__(256) void embed_kernel(
    const int* __restrict__ node_type, const float* __restrict__ nif,
    const int* __restrict__ in_deg, const int* __restrict__ out_deg,
    const float* __restrict__ node_emb, const float* __restrict__ ind_emb,
    const float* __restrict__ outd_emb,
    float* __restrict__ x, u16* __restrict__ xb)
{
  const int r = blockIdx.x;           // r = n*B + b
  const int n = r / Bb, b = r % Bb;
  const int nt  = node_type[b*Nn + n];
  const int idg = in_deg[b*Nn + n];
  const int odg = out_deg[b*Nn + n];
  for (int c = threadIdx.x; c < Ee; c += 256) {
    float val = node_emb[(size_t)nt*Ee + c] + ind_emb[(size_t)idg*Ee + c]
              + outd_emb[(size_t)odg*Ee + c] + nif[((size_t)b*Nn + n)*Ee + c];
    x[(size_t)r*Ee + c] = val;
    xb[(size_t)r*Ee + c] = f2b(val);
  }
}

// ---------------- spatial_pos transpose
__global__ void spT_kernel(const int* __restrict__ sp, int* __restrict__ spT)
{
  __shared__ int tile[32][33];
  const int b = blockIdx.z;
  const int n0 = blockIdx.y * 32, m0 = blockIdx.x * 32;
  const int tx = threadIdx.x, ty = threadIdx.y;
  for (int i = ty; i < 32; i += 8)
    tile[i][tx] = sp[((size_t)b*Nn + n0 + i)*Nn + m0 + tx];
  __syncthreads();
  for (int i = ty; i < 32; i += 8)
    spT[((size_t)b*Nn + m0 + i)*Nn + n0 + tx] = tile[tx][i];
}

// ---------------- bias precompute into MFMA-fragment chunk layout:
// flat[(((b*H+h)*24 + bx)*24 + tt)*256 + hi*64 + ql*4 + j]
//   = bias(b, h, q = bx*16 + ql, m = tt*16 + hi*4 + j)
__global__ __launch_bounds__(256) void bias_pre_kernel(
    const float* __restrict__ atb, const int* __restrict__ sp, const int* __restrict__ spT,
    const float* __restrict__ sp_emb, const float* __restrict__ sp_emb_rev,
    u16* __restrict__ biasb)
{
  __shared__ float spc[512], sprc[512];
  const int bx = blockIdx.x, h = blockIdx.y, b = blockIdx.z;
  const int t = threadIdx.x;
  for (int i = t; i < 512; i += 256) {
    spc[i]  = sp_emb[(size_t)i*Hh + h];
    sprc[i] = sp_emb_rev[(size_t)i*Hh + h];
  }
  __syncthreads();
  const int q = bx*16 + ((t >> 2) & 15);
  const size_t rowb = ((size_t)b*Nn + q)*Nn;
  u16* outb = biasb + (((size_t)(b*Hh + h)*24 + bx)*24)*256 + t;
  const int mbase = ((t >> 6) << 2) + (t & 3);
  for (int tt = 0; tt < 24; ++tt) {
    const int m = tt*16 + mbase;
    float v = atb[rowb + m] + spc[sp[rowb + m]] + sprc[spT[rowb + m]];
    outb[tt*256] = f2b(v);
  }
}

// ---------------- weight transpose+convert: src f32 [Ks][Ns] -> dst bf16 [Ns][Ks]
// LDS stride 65 floats: both phases provably uniform 2-way (= conflict-free, m136)
__global__ __launch_bounds__(256) void wconv_kernel(
    const float* __restrict__ Wq, const float* __restrict__ Wk, const float* __restrict__ Wv,
    const float* __restrict__ Wo, const float* __restrict__ W1, const float* __restrict__ W2,
    int layer0, u16* __restrict__ wTall, unsigned slotStride)
{
  __shared__ float tile[64][65];
  const int layer = layer0 + blockIdx.y;
  u16* slot = wTall + (size_t)blockIdx.y * slotStride;
  int tid = blockIdx.x;
  const float* src; u16* dst; int Ns, Ks;
  if (tid < 432)       { int seg = tid / 144; tid -= seg*144;
                         src = (seg==0?Wq:(seg==1?Wk:Wv)) + (size_t)layer*Ee*Ee;
                         dst = slot + (size_t)seg*589824; Ns = 768; Ks = 768; }
  else if (tid < 576)  { tid -= 432; src = Wo + (size_t)layer*Ee*Ee; dst = slot + 1769472; Ns = 768;  Ks = 768; }
  else if (tid < 1152) { tid -= 576; src = W1 + (size_t)layer*Ee*Ff; dst = slot + 2359296; Ns = 3072; Ks = 768; }
  else                 { tid -= 1152; src = W2 + (size_t)layer*Ff*Ee; dst = slot + 4718592; Ns = 768; Ks = 3072; }
  const int tc = Ns >> 6;
  const int tk = tid / tc, tn = tid % tc;
  const int t = threadIdx.x;
  #pragma unroll
  for (int i = 0; i < 4; ++i) {
    const int id = t + i*256;
    const int r = id >> 4, c = (id & 15) << 2;
    float4 v = *(const float4*)(src + (size_t)(tk*64 + r)*Ns + tn*64 + c);
    tile[r][c+0] = v.x; tile[r][c+1] = v.y; tile[r][c+2] = v.z; tile[r][c+3] = v.w;
  }
  __syncthreads();
  #pragma unroll
  for (int i = 0; i < 2; ++i) {
    const int ch = t + i*256;
    const int n = ch >> 3, kc = (ch & 7) << 3;
    uint4 u;
    u.x = pkcvt(tile[kc+0][n], tile[kc+1][n]);
    u.y = pkcvt(tile[kc+2][n], tile[kc+3][n]);
    u.z = pkcvt(tile[kc+4][n], tile[kc+5][n]);
    u.w = pkcvt(tile[kc+6][n], tile[kc+7][n]);
    *(uint4*)(dst + (size_t)(tn*64 + n)*Ks + tk*64 + kc) = u;
  }
}

// ---------------- 128x64-tile GEMM, BK=64, counted-vmcnt 2-barrier pipeline, XCD-swizzled
// 4 waves, each 64m x 32n (FR 4x2): 16 MFMA : 12 ds_read_b128 per k-step.
// LDS rows 128B; source pre-swizzled (slot ^= row&7), swizzled ds_read recovers (rule #21).
// EPI 0: qkv fused bias (Q scaled) -> bf16 out ld 2304
// EPI 1: f32 partial out ld 768 (bias only on z==0)
// EPI 2: gelu -> bf16 out ld 3072
template<int EPI>
__global__ __launch_bounds__(256) void gemm3_kernel(
    const u16* __restrict__ A, const u16* __restrict__ Bw,
    const float* __restrict__ b0, const float* __restrict__ b1, const float* __restrict__ b2,
    int Kfull, int Kc, float scaleQ,
    float* __restrict__ outF, u16* __restrict__ outB)
{
  __shared__ __align__(16) u16 As[2][128][64];
  __shared__ __align__(16) u16 Bs[2][64][64];
  const int t = threadIdx.x, lane = t & 63, wave = t >> 6;
  int bx = blockIdx.x, by = blockIdx.y;
  { // XCD swizzle (xy grid always divisible by 8)
    const int gx = gridDim.x;
    const int nwg = gx * gridDim.y;
    const int bid = bx + gx * by;
    const int cpx = nwg >> 3;
    const int s = (bid & 7) * cpx + (bid >> 3);
    bx = s % gx; by = s / gx;
  }
  const int m0 = bx * 128, n0 = by * 64;
  const int k0 = blockIdx.z * Kc;
  const int wm = wave >> 1, wn = wave & 1;
  const int ql = lane & 15, hi = lane >> 4;
  const int nk = Kc >> 6;
  // staging map: thread t covers row (i*32 + t>>3), 16B slot (t&7), source slot XOR'd
  const int sr = t >> 3;
  const int sslot = (t & 7) ^ (sr & 7);
  const size_t aoff = (size_t)(m0 + sr)*Kfull + k0 + (sslot << 3);
  const size_t boff = (size_t)(n0 + sr)*Kfull + k0 + (sslot << 3);
  const size_t rstep = (size_t)32 * Kfull;

  // fragment LDS byte offsets (row&7 == ql&7 for all fragment rows)
  int aro[4][2], bro[2][2];
  #pragma unroll
  for (int ks = 0; ks < 2; ++ks) {
    const int kb = (((ks<<2) + hi) ^ (ql & 7)) << 4;
    #pragma unroll
    for (int f = 0; f < 4; ++f) aro[f][ks] = (wm*64 + f*16 + ql)*128 + kb;
    #pragma unroll
    for (int f = 0; f < 2; ++f) bro[f][ks] = (wn*32 + f*16 + ql)*128 + kb;
  }

  f32x4 acc[4][2];
  #pragma unroll
  for (int a = 0; a < 4; ++a)
    #pragma unroll
    for (int c = 0; c < 2; ++c) acc[a][c] = (f32x4){0.f,0.f,0.f,0.f};

  // prologue: issue tile 0 (first loop iteration's vmcnt+B1 covers it)
  #pragma unroll
  for (int i = 0; i < 4; ++i)
    gload_lds16(A + aoff + i*rstep, (char*)&As[0][0][0] + i*4096 + t*16);
  #pragma unroll
  for (int i = 0; i < 2; ++i)
    gload_lds16(Bw + boff + i*rstep, (char*)&Bs[0][0][0] + i*4096 + t*16);

  for (int kt = 0; kt < nk; ++kt) {
    const int cur = kt & 1, nxt = cur ^ 1;
    const bool pre = (kt + 1 < nk);
    if (pre) {
      const size_t kk = (size_t)(kt + 1) << 6;
      #pragma unroll
      for (int i = 0; i < 4; ++i)
        gload_lds16(A + aoff + kk + i*rstep, (char*)&As[nxt][0][0] + i*4096 + t*16);
      #pragma unroll
      for (int i = 0; i < 2; ++i)
        gload_lds16(Bw + boff + kk + i*rstep, (char*)&Bs[nxt][0][0] + i*4096 + t*16);
      asm volatile("s_waitcnt vmcnt(6)" ::: "memory");   // tile kt landed; kt+1 in flight
    } else {
      asm volatile("s_waitcnt vmcnt(0)" ::: "memory");
    }
    __builtin_amdgcn_s_barrier();            // B1
    __builtin_amdgcn_sched_barrier(0);

    const char* aBase = (const char*)&As[cur][0][0];
    const char* bBase = (const char*)&Bs[cur][0][0];
    bf16x8 af[4][2], bf[2][2];
    #pragma unroll
    for (int f = 0; f < 4; ++f)
      #pragma unroll
      for (int ks = 0; ks < 2; ++ks)
        af[f][ks] = *(const bf16x8*)(aBase + aro[f][ks]);
    #pragma unroll
    for (int f = 0; f < 2; ++f)
      #pragma unroll
      for (int ks = 0; ks < 2; ++ks)
        bf[f][ks] = *(const bf16x8*)(bBase + bro[f][ks]);
    #pragma unroll
    for (int ks = 0; ks < 2; ++ks)
      #pragma unroll
      for (int fm = 0; fm < 4; ++fm)
        #pragma unroll
        for (int fn = 0; fn < 2; ++fn)
          acc[fm][fn] = __builtin_amdgcn_mfma_f32_16x16x32_bf16(af[fm][ks], bf[fn][ks], acc[fm][fn], 0, 0, 0);
    if (pre) {
      __builtin_amdgcn_sched_barrier(0);
      __builtin_amdgcn_s_barrier();          // B2: cur reads drained before overwrite
    }
  }

  #pragma unroll
  for (int fm = 0; fm < 4; ++fm) {
    const int rowb = m0 + wm*64 + fm*16 + hi*4;
    #pragma unroll
    for (int fn = 0; fn < 2; ++fn) {
      const int gcol = n0 + wn*32 + fn*16 + ql;
      float bv, scale = 1.0f;
      if (EPI == 0) {
        const int seg = gcol / 768;
        const int cw = gcol - seg*768;
        bv = (seg == 0) ? b0[cw] : ((seg == 1) ? b1[cw] : b2[cw]);
        if (seg == 0) scale = scaleQ;
      } else if (EPI == 1) {
        bv = (blockIdx.z == 0) ? b0[gcol] : 0.0f;
      } else {
        bv = b0[gcol];
      }
      f32x4 v = acc[fm][fn];
      #pragma unroll
      for (int j = 0; j < 4; ++j) {
        float val = (v[j] + bv) * scale;
        if (EPI == 0) {
          outB[(size_t)(rowb + j) * 2304 + gcol] = f2b(val);
        } else if (EPI == 1) {
          outF[(size_t)blockIdx.z * (Mm*768) + (size_t)(rowb + j) * 768 + gcol] = val;
        } else {
          float arg = 0.7978845608028654f * (val + 0.044715f * val * val * val);
          float e = __expf(2.0f * arg);
          float g = 0.5f * val * (2.0f - 2.0f / (e + 1.0f));
          outB[(size_t)(rowb + j) * 3072 + gcol] = f2b(g);
        }
      }
    }
  }
}

// ---------------- MFMA attention: block = (b, h, pair of 64-q-row tiles)
template<int PREBIAS>
__global__ __launch_bounds__(256) void attn2_kernel(
    const u16* __restrict__ qkv,         // [1536][2304] bf16 q|k|v (q pre-scaled)
    const u16* __restrict__ biasb,       // chunk layout (PREBIAS=1)
    const float* __restrict__ atb, const int* __restrict__ sp, const int* __restrict__ spT,
    const float* __restrict__ sp_emb, const float* __restrict__ sp_emb_rev,
    u16* __restrict__ ab)                // [1536][768] bf16
{
  __shared__ __align__(16) u16 Kt[384][32];   // [m][d(24)+pad]
  __shared__ __align__(16) u16 Vt[32][392];   // [d(24)+pad][m] transposed
  __shared__ __align__(16) u16 Qt[64][32];
  __shared__ __align__(16) u16 Pw[4][16][32]; // per-wave P chunk
  __shared__ float spc[512], sprc[512];
  const int bid = blockIdx.x;
  const int pair = bid % 3;
  const int h = (bid / 3) % Hh;
  const int b = bid / (3 * Hh);
  const int t = threadIdx.x, lane = t & 63, wave = t >> 6;
  const int ql = lane & 15, hi = lane >> 4;

  for (int idx = t; idx < 384*6; idx += 256) {
    const int m = idx / 6, c = idx - m*6;
    const u16* base = qkv + ((size_t)m*Bb + b)*2304 + h*24 + c*4;
    uint2 kk = *(const uint2*)(base + 768);
    uint2 vv = *(const uint2*)(base + 1536);
    *(uint2*)&Kt[m][c*4] = kk;
    Vt[c*4+0][m] = (u16)(vv.x & 0xffffu); Vt[c*4+1][m] = (u16)(vv.x >> 16);
    Vt[c*4+2][m] = (u16)(vv.y & 0xffffu); Vt[c*4+3][m] = (u16)(vv.y >> 16);
  }
  for (int idx = t; idx < 384*2; idx += 256)           // K d-pad
    *(uint2*)&Kt[idx>>1][24 + (idx&1)*4] = make_uint2(0u, 0u);
  for (int idx = t; idx < 8*196; idx += 256)           // V^T d-pad rows
    *(unsigned*)((char*)&Vt[24][0] + idx*4) = 0u;
  if (!PREBIAS) {
    for (int i = t; i < 512; i += 256) {
      spc[i]  = sp_emb[(size_t)i*Hh + h];
      sprc[i] = sp_emb_rev[(size_t)i*Hh + h];
    }
  }

  for (int qi = 0; qi < 2; ++qi) {
    const int ntile = pair*2 + qi;
    for (int idx = t; idx < 64*6; idx += 256) {
      const int qr = idx / 6, c = idx - qr*6;
      const u16* base = qkv + ((size_t)(ntile*64 + qr)*Bb + b)*2304 + h*24 + c*4;
      *(uint2*)&Qt[qr][c*4] = *(const uint2*)base;
    }
    for (int idx = t; idx < 64*2; idx += 256)
      *(uint2*)&Qt[idx>>1][24 + (idx&1)*4] = make_uint2(0u, 0u);
    __syncthreads();   // covers K/V/Qt staging (iter 0) and Qt restage (iter 1)

    const int q0 = ntile*64 + wave*16;
    const int q = q0 + ql;
    const bf16x8 qf = *(const bf16x8*)&Qt[wave*16 + ql][hi*8];

    f32x4 f[24];
    const u16* bp = biasb + (((size_t)(b*Hh + h)*24 + ntile*4 + wave)*24)*256 + lane*4;
    const size_t crow = ((size_t)b*Nn + q)*Nn;
    #pragma unroll
    for (int tt = 0; tt < 24; ++tt) {
      bf16x8 kf = *(const bf16x8*)&Kt[tt*16 + ql][hi*8];
      f32x4 z = (f32x4){0.f,0.f,0.f,0.f};
      f32x4 s = __builtin_amdgcn_mfma_f32_16x16x32_bf16(kf, qf, z, 0, 0, 0);
      if (PREBIAS) {
        uint2 bb = *(const uint2*)(bp + tt*256);
        s[0] += b2f((u16)(bb.x & 0xffffu)); s[1] += b2f((u16)(bb.x >> 16));
        s[2] += b2f((u16)(bb.y & 0xffffu)); s[3] += b2f((u16)(bb.y >> 16));
      } else {
        const int off = tt*16 + hi*4;
        int4 s4 = *(const int4*)(sp + crow + off);
        int4 t4 = *(const int4*)(spT + crow + off);
        float4 a4 = *(const float4*)(atb + crow + off);
        s[0] += a4.x + spc[s4.x] + sprc[t4.x];
        s[1] += a4.y + spc[s4.y] + sprc[t4.y];
        s[2] += a4.z + spc[s4.z] + sprc[t4.z];
        s[3] += a4.w + spc[s4.w] + sprc[t4.w];
      }
      f[tt] = s;
    }

    float mx = -3.0e38f;
    #pragma unroll
    for (int tt = 0; tt < 24; ++tt)
      mx = fmaxf(mx, fmaxf(fmaxf(f[tt][0], f[tt][1]), fmaxf(f[tt][2], f[tt][3])));
    mx = fmaxf(mx, __shfl_xor(mx, 16, 64));
    mx = fmaxf(mx, __shfl_xor(mx, 32, 64));
    float sum = 0.f;
    #pragma unroll
    for (int tt = 0; tt < 24; ++tt) {
      #pragma unroll
      for (int j = 0; j < 4; ++j) { f[tt][j] = __expf(f[tt][j] - mx); sum += f[tt][j]; }
    }
    sum += __shfl_xor(sum, 16, 64);
    sum += __shfl_xor(sum, 32, 64);
    const float inv = 1.0f / sum;

    f32x4 o0 = (f32x4){0.f,0.f,0.f,0.f}, o1 = (f32x4){0.f,0.f,0.f,0.f};
    char* prow = (char*)&Pw[wave][ql][0];
    const int swz = (ql & 3) << 4;
    #pragma unroll
    for (int c = 0; c < 12; ++c) {
      unsigned w0 = pkcvt(f[2*c][0],   f[2*c][1]);
      unsigned w1 = pkcvt(f[2*c][2],   f[2*c][3]);
      unsigned w2 = pkcvt(f[2*c+1][0], f[2*c+1][1]);
      unsigned w3 = pkcvt(f[2*c+1][2], f[2*c+1][3]);
      *(unsigned*)(prow + (((hi*8)      ) ^ swz)) = w0;
      *(unsigned*)(prow + (((hi*8) +  4) ^ swz)) = w1;
      *(unsigned*)(prow + (((hi*8) + 32) ^ swz)) = w2;
      *(unsigned*)(prow + (((hi*8) + 36) ^ swz)) = w3;
      bf16x8 a = *(const bf16x8*)(prow + ((hi*16) ^ swz));
      bf16x8 v0 = *(const bf16x8*)&Vt[ql][c*32 + hi*8];
      bf16x8 v1 = *(const bf16x8*)&Vt[16 + ql][c*32 + hi*8];
      o0 = __builtin_amdgcn_mfma_f32_16x16x32_bf16(a, v0, o0, 0, 0, 0);
      o1 = __builtin_amdgcn_mfma_f32_16x16x32_bf16(a, v1, o1, 0, 0, 0);
    }

    #pragma unroll
    for (int j = 0; j < 4; ++j) {
      float invj = __shfl(inv, hi*4 + j, 64);
      const int qg = q0 + hi*4 + j;
      u16* orow = ab + ((size_t)qg*Bb + b)*Ee + h*24;
      orow[ql] = f2b(o0[j] * invj);
      if (ql < 8) orow[16 + ql] = f2b(o1[j] * invj);
    }
    __syncthreads();   // protect Qt before restage
  }
}

// ---------------- residual + LayerNorm, sums NP split-K partials
template<int NP>
__global__ __launch_bounds__(256) void ln_kernel(
    const float* __restrict__ xin, const float* __restrict__ delta,
    const float* __restrict__ gamma, const float* __restrict__ beta,
    float* __restrict__ xout, u16* __restrict__ xb)
{
  __shared__ float red[8];
  const int r = blockIdx.x, t = threadIdx.x;
  const size_t base = (size_t)r * Ee;
  float v[3];
  #pragma unroll
  for (int i = 0; i < 3; ++i) {
    int c = t + i*256;
    float d = xin[base + c];
    #pragma unroll
    for (int p = 0; p < NP; ++p) d += delta[(size_t)p*(Mm*768) + base + c];
    v[i] = d;
  }
  float s = v[0] + v[1] + v[2];
  #pragma unroll
  for (int off = 1; off < 64; off <<= 1) s += __shfl_xor(s, off, 64);
  if ((t & 63) == 0) red[t >> 6] = s;
  __syncthreads();
  const float mean = (red[0] + red[1] + red[2] + red[3]) * (1.0f / 768.0f);
  float qs = 0.f;
  #pragma unroll
  for (int i = 0; i < 3; ++i) { float d = v[i] - mean; qs += d * d; }
  #pragma unroll
  for (int off = 1; off < 64; off <<= 1) qs += __shfl_xor(qs, off, 64);
  if ((t & 63) == 0) red[4 + (t >> 6)] = qs;
  __syncthreads();
  const float var = (red[4] + red[5] + red[6] + red[7]) * (1.0f / 768.0f);
  const float rstd = rsqrtf(var + 1e-5f);
  #pragma unroll
  for (int i = 0; i < 3; ++i) {
    int c = t + i*256;
    float o = (v[i] - mean) * rstd * gamma[c] + beta[c];
    xout[base + c] = o;
    xb[base + c] = f2b(o);
  }
}

extern "C" void kernel_launch(void* const* d_in, const int* in_sizes, int n_in,
                              void* d_out, int out_size, void* d_ws, size_t ws_size,
                              hipStream_t stream) {
  const int*   node_type  = (const int*)d_in[0];
  const float* nif        = (const float*)d_in[1];
  const int*   in_deg     = (const int*)d_in[2];
  const int*   out_deg    = (const int*)d_in[3];
  const float* atb        = (const float*)d_in[4];
  const int*   sp         = (const int*)d_in[5];
  const float* node_emb   = (const float*)d_in[6];
  const float* ind_emb    = (const float*)d_in[7];
  const float* outd_emb   = (const float*)d_in[8];
  const float* sp_emb     = (const float*)d_in[9];
  const float* sp_emb_rev = (const float*)d_in[10];
  const float* Wq = (const float*)d_in[11]; const float* bq = (const float*)d_in[12];
  const float* Wk = (const float*)d_in[13]; const float* bk = (const float*)d_in[14];
  const float* Wv = (const float*)d_in[15]; const float* bv = (const float*)d_in[16];
  const float* Wo = (const float*)d_in[17]; const float* bo = (const float*)d_in[18];
  const float* W1 = (const float*)d_in[19]; const float* b1 = (const float*)d_in[20];
  const float* W2 = (const float*)d_in[21]; const float* b2 = (const float*)d_in[22];
  const float* ln1s = (const float*)d_in[23]; const float* ln1b = (const float*)d_in[24];
  const float* ln2s = (const float*)d_in[25]; const float* ln2b = (const float*)d_in[26];

  char* ws = (char*)d_ws;
  float* x      = (float*)(ws);                    //  4,718,592
  u16*   xb     = (u16*)(ws +  4718592);           //  2,359,296
  u16*   qkvb16 = (u16*)(ws +  7077888);           //  7,077,888
  u16*   abuf   = (u16*)(ws + 14155776);           //  2,359,296
  u16*   hb     = (u16*)(ws + 16515072);           //  9,437,184
  float* obufP  = (float*)(ws + 25952256);         // 18,874,368 (4 partials)
  int*   spTb   = (int*)(ws + 44826624);           //  2,359,296
  u16*   biasb  = (u16*)(ws + 47185920);           // 37,748,736 -> 84,934,656
  const bool useBias = ws_size >= 99090432ull;
  const bool allW    = ws_size >= 254803968ull;
  u16* wTall = (u16*)(ws + (useBias ? 84934656 : 47185920));
  const unsigned LSLOT = 7077888u;   // u16 elements per layer slot

  embed_kernel<<<Mm, 256, 0, stream>>>(node_type, nif, in_deg, out_deg,
                                       node_emb, ind_emb, outd_emb, x, xb);
  spT_kernel<<<dim3(12, 12, 4), dim3(32, 8), 0, stream>>>(sp, spTb);
  if (useBias)
    bias_pre_kernel<<<dim3(24, 32, 4), 256, 0, stream>>>(atb, sp, spTb, sp_emb, sp_emb_rev, biasb);
  if (allW)
    wconv_kernel<<<dim3(1728, 12), 256, 0, stream>>>(Wq, Wk, Wv, Wo, W1, W2,
                                                     0, wTall, LSLOT);

  const float scaleQ = 0.2041241452319315f;  // 24^-0.5

  for (int l = 0; l < Ll; ++l) {
    const float *bql = bq + (size_t)l*Ee, *bkl = bk + (size_t)l*Ee, *bvl = bv + (size_t)l*Ee;
    const float *bol = bo + (size_t)l*Ee;
    const float *b1l = b1 + (size_t)l*Ff, *b2l = b2 + (size_t)l*Ee;

    if (!allW)
      wconv_kernel<<<dim3(1728, 1), 256, 0, stream>>>(Wq, Wk, Wv, Wo, W1, W2,
                                                      l, wTall, 0u);
    u16* slot = wTall + (size_t)(allW ? l : 0) * LSLOT;
    const u16* qkvT = slot;
    const u16* woT  = slot + 1769472;
    const u16* w1T  = slot + 2359296;
    const u16* w2T  = slot + 4718592;

    // QKV: [1536,768] @ [2304,768]^T -> bf16 [1536][2304]
    gemm3_kernel<0><<<dim3(12, 36), 256, 0, stream>>>(xb, qkvT, bql, bkl, bvl,
                                                      768, 768, scaleQ, nullptr, qkvb16);
    if (useBias)
      attn2_kernel<1><<<384, 256, 0, stream>>>(qkvb16, biasb, atb, sp, spTb,
                                               sp_emb, sp_emb_rev, abuf);
    else
      attn2_kernel<0><<<384, 256, 0, stream>>>(qkvb16, nullptr, atb, sp, spTb,
                                               sp_emb, sp_emb_rev, abuf);
    // O-proj: split-K 2 -> partials
    gemm3_kernel<1><<<dim3(12, 12, 2), 256, 0, stream>>>(abuf, woT, bol, bol, bol,
                                                         768, 384, 1.0f, obufP, nullptr);
    ln_kernel<2><<<Mm, 256, 0, stream>>>(x, obufP, ln1s + (size_t)l*Ee, ln1b + (size_t)l*Ee, x, xb);
    // FFN1 + gelu -> bf16 hidden
    gemm3_kernel<2><<<dim3(12, 48), 256, 0, stream>>>(xb, w1T, b1l, b1l, b1l,
                                                      768, 768, 1.0f, nullptr, hb);
    // FFN2: split-K 4 -> partials
    gemm3_kernel<1><<<dim3(12, 12, 4), 256, 0, stream>>>(hb, w2T, b2l, b2l, b2l,
                                                         3072, 768, 1.0f, obufP, nullptr);
    float* xdst = (l == Ll - 1) ? (float*)d_out : x;
    ln_kernel<4><<<Mm, 256, 0, stream>>>(x, obufP, ln2s + (size_t)l*Ee, ln2b + (size_t)l*Ee, xdst, xb);
  }
}